// Round 5
// baseline (1029.880 us; speedup 1.0000x reference)
//
#include <hip/hip_runtime.h>
#include <hip/hip_bf16.h>
#include <math.h>

#define NQ 30000
#define NS 400
#define DD 128
#define HH 128
#define SS 200
#define BB 256
#define MSq 4
#define MBs 4
#define PP 512
#define SB (SS*BB)      // 51200
#define G3 384          // 3*H
#define QPB 16

typedef __hip_bfloat16 bf16;
typedef __attribute__((ext_vector_type(8))) short bf16x8;
typedef __attribute__((ext_vector_type(4))) float f32x4;

__device__ __forceinline__ float sigf(float x){ return 1.0f/(1.0f+expf(-x)); }
__device__ __forceinline__ float bf2f(unsigned short u){
  unsigned int x = ((unsigned int)u)<<16;
  return __uint_as_float(x);
}

// ---------------- tables: T_ans = ans_emb @ Wi[:,0:128].T etc ----------------
__global__ __launch_bounds__(128) void tables_k(const float* __restrict__ ans_emb,
        const float* __restrict__ label_emb, const float* __restrict__ Wi,
        float* __restrict__ Tans, float* __restrict__ Tcae, float* __restrict__ Tlab){
  int j = blockIdx.x*128 + threadIdx.x;
  if (j >= G3) return;
  const float* wr = Wi + (size_t)j*640;
  for (int a=0;a<4;a++){
    float acc=0.f;
    for (int k=0;k<DD;k++) acc += ans_emb[a*DD+k]*wr[k];
    Tans[a*G3+j]=acc;
  }
  for (int a=0;a<4;a++){
    float acc=0.f;
    for (int k=0;k<DD;k++) acc += ans_emb[a*DD+k]*wr[128+k];
    Tcae[a*G3+j]=acc;
  }
  for (int l=0;l<2;l++){
    float acc=0.f;
    for (int k=0;k<DD;k++) acc += label_emb[l*DD+k]*wr[256+k];
    Tlab[l*G3+j]=acc;
  }
}

// ---------------- weight convert: f32 -> bf16 ----------------
__global__ __launch_bounds__(256) void conv_w_k(const float* __restrict__ l1W,
        const float* __restrict__ l2W, const float* __restrict__ Wi,
        bf16* __restrict__ l1Wb, bf16* __restrict__ l2Wb, bf16* __restrict__ WiB){
  int i = blockIdx.x*256 + threadIdx.x;
  if (i < 512*512){
    l1Wb[i] = __float2bfloat16(l1W[i]);
    l2Wb[i] = __float2bfloat16(l2W[i]);
  }
  if (i < 384*256){
    int j = i >> 8, k = i & 255;
    WiB[i] = __float2bfloat16(Wi[j*640 + 384 + k]);
  }
}

// ---------------- q2s projection + scatter to subject sums ----------------
__global__ __launch_bounds__(128) void q2s_scatter(const float* __restrict__ q_emb,
        const float* __restrict__ W, const float* __restrict__ bias,
        const int* __restrict__ q_map, float* __restrict__ sums, float* __restrict__ cnts){
  __shared__ float qe[QPB][DD];
  int q0 = blockIdx.x*QPB;
  int tid = threadIdx.x;
  for (int r=0;r<QPB;r++) qe[r][tid] = q_emb[(size_t)(q0+r)*DD + tid];
  __syncthreads();
  float acc[QPB];
  #pragma unroll
  for (int r=0;r<QPB;r++) acc[r] = bias[tid];
  const float4* wr = (const float4*)(W + (size_t)tid*DD);
  #pragma unroll 4
  for (int k4=0;k4<DD/4;k4++){
    float4 w = wr[k4];
    #pragma unroll
    for (int r=0;r<QPB;r++){
      acc[r] += w.x*qe[r][k4*4] + w.y*qe[r][k4*4+1] + w.z*qe[r][k4*4+2] + w.w*qe[r][k4*4+3];
    }
  }
  for (int r=0;r<QPB;r++){
    int q = q0+r;
    #pragma unroll
    for (int m=0;m<MSq;m++){
      int s = q_map[q*MSq+m];
      atomicAdd(&sums[(size_t)s*DD + tid], acc[r]);
      if (tid==0) atomicAdd(&cnts[s], 1.0f);
    }
  }
}

// ---------------- subjects_1 ----------------
__global__ __launch_bounds__(128) void subjects1_k(const float* __restrict__ s_emb,
        const float* __restrict__ W, const float* __restrict__ bias,
        const float* __restrict__ sums, const float* __restrict__ cnts,
        float* __restrict__ out){
  __shared__ float se[DD];
  int s = blockIdx.x; int tid = threadIdx.x;
  se[tid] = s_emb[(size_t)s*DD+tid];
  __syncthreads();
  float acc = bias[tid];
  const float4* wr = (const float4*)(W + (size_t)tid*DD);
  for (int k4=0;k4<DD/4;k4++){
    float4 w = wr[k4];
    acc += w.x*se[k4*4] + w.y*se[k4*4+1] + w.z*se[k4*4+2] + w.w*se[k4*4+3];
  }
  float c = cnts[s];
  float v = 0.f;
  if (c > 0.f) v = tanhf(sums[(size_t)s*DD+tid]/fmaxf(c,1.f) + acc);
  out[(size_t)s*DD+tid] = v;
}

// ---------------- questions_1 (bf16 out) ----------------
__global__ __launch_bounds__(128) void questions1_k(const float* __restrict__ q_emb,
        const float* __restrict__ subj1, const int* __restrict__ q_map,
        const float* __restrict__ q_mask,
        const float* __restrict__ s2qW, const float* __restrict__ s2qb,
        const float* __restrict__ q2qW, const float* __restrict__ q2qb,
        bf16* __restrict__ q1out){
  __shared__ float qe[QPB][DD];
  __shared__ float nq[QPB][DD];
  int q0 = blockIdx.x*QPB; int tid = threadIdx.x;
  for (int r=0;r<QPB;r++){
    int q = q0+r;
    qe[r][tid] = q_emb[(size_t)q*DD+tid];
    float sum=0.f, wsum=0.f;
    #pragma unroll
    for (int m=0;m<MSq;m++){
      float w = q_mask[q*MSq+m];
      sum += subj1[(size_t)q_map[q*MSq+m]*DD + tid]*w;
      wsum += w;
    }
    nq[r][tid] = sum / wsum;
  }
  __syncthreads();
  float acc[QPB];
  #pragma unroll
  for (int r=0;r<QPB;r++) acc[r] = s2qb[tid]+q2qb[tid];
  const float4* w1 = (const float4*)(s2qW + (size_t)tid*DD);
  const float4* w2 = (const float4*)(q2qW + (size_t)tid*DD);
  #pragma unroll 2
  for (int k4=0;k4<DD/4;k4++){
    float4 a = w1[k4]; float4 b = w2[k4];
    #pragma unroll
    for (int r=0;r<QPB;r++){
      acc[r] += a.x*nq[r][k4*4] + a.y*nq[r][k4*4+1] + a.z*nq[r][k4*4+2] + a.w*nq[r][k4*4+3]
              + b.x*qe[r][k4*4] + b.y*qe[r][k4*4+1] + b.z*qe[r][k4*4+2] + b.w*qe[r][k4*4+3];
    }
  }
  for (int r=0;r<QPB;r++) q1out[(size_t)(q0+r)*DD+tid] = __float2bfloat16(tanhf(acc[r]));
}

// ---------------- assemble pred_input cols 0:256 and 384:512 (bf16) ----------------
__global__ __launch_bounds__(128) void assemble_k(const bf16* __restrict__ q1,
        const float* __restrict__ subj1, const float* __restrict__ ans_emb,
        const int* __restrict__ cans, const int* __restrict__ sub_ids,
        const float* __restrict__ sub_mask, const int* __restrict__ q_ids,
        bf16* __restrict__ pred){
  int i = blockIdx.x; int d = threadIdx.x;
  size_t base = (size_t)i*PP;
  pred[base + d] = q1[(size_t)q_ids[i]*DD + d];
  float s = 0.f;
  #pragma unroll
  for (int m=0;m<MBs;m++)
    s += subj1[(size_t)sub_ids[i*MBs+m]*DD+d]*sub_mask[i*MBs+m];
  pred[base+128+d] = __float2bfloat16(s);
  pred[base+384+d] = __float2bfloat16(ans_emb[(size_t)cans[i]*DD + d]);
}

// ======== MFMA GEMM core: C[128x128] tile = A[128xK] @ Bw[128xK]^T ========
// A row-major bf16 (lda elements), Bw row-major bf16 [n][k] (ldb elements).
// 256 threads = 4 waves in 2x2 grid; each wave 64x64 = 4x4 fragments of 16x16.
// Fragments loaded directly from global (no LDS, no barriers -> compiler pipelines).
// Layouts (m89/m97-verified): A/B frag: lane&15 = row(col), k = (lane>>4)*8+j.
// C/D: col = lane&15, row = (lane>>4)*4 + reg.
#define MFMA_CORE(A_, lda_, B_, ldb_, K_) \
  int lane = threadIdx.x & 63; int wid = threadIdx.x >> 6; \
  int wy = wid >> 1, wx = wid & 1; \
  int mbase = blockIdx.x*128 + wy*64; \
  int nbase = blockIdx.y*128 + wx*64; \
  int lr = lane & 15, kg = (lane >> 4) * 8; \
  f32x4 acc[4][4]; \
  _Pragma("unroll") for (int i=0;i<4;i++) _Pragma("unroll") for (int j=0;j<4;j++) acc[i][j] = (f32x4){0.f,0.f,0.f,0.f}; \
  for (int k=0; k<(K_); k+=32){ \
    bf16x8 af[4], bfr[4]; \
    _Pragma("unroll") for (int mi=0;mi<4;mi++) \
      af[mi] = *(const bf16x8*)((A_) + (size_t)(mbase+mi*16+lr)*(lda_) + k + kg); \
    _Pragma("unroll") for (int ni=0;ni<4;ni++) \
      bfr[ni] = *(const bf16x8*)((B_) + (size_t)(nbase+ni*16+lr)*(ldb_) + k + kg); \
    _Pragma("unroll") for (int mi=0;mi<4;mi++) \
      _Pragma("unroll") for (int ni=0;ni<4;ni++) \
        acc[mi][ni] = __builtin_amdgcn_mfma_f32_16x16x32_bf16(af[mi], bfr[ni], acc[mi][ni], 0, 0, 0); \
  }

// ---------------- xp = pred[:,0:256]@WiB.T + tables + bi ----------------
__global__ __launch_bounds__(256) void gemm_xp(const bf16* __restrict__ pred,
        const bf16* __restrict__ WiB, const float* __restrict__ bi,
        const float* __restrict__ Tans, const float* __restrict__ Tcae,
        const float* __restrict__ Tlab,
        const float* __restrict__ tm, const float* __restrict__ vm,
        const float* __restrict__ lm,
        const int* __restrict__ ans, const int* __restrict__ cans,
        const float* __restrict__ labels, float* __restrict__ xp){
  MFMA_CORE(pred, PP, WiB, 256, 256)
  #pragma unroll
  for (int mi=0;mi<4;mi++){
    #pragma unroll
    for (int r=0;r<4;r++){
      int row = mbase + mi*16 + (lane>>4)*4 + r;
      float mk = tm[row]*vm[row]*lm[row];
      int a = ans[row], ca = cans[row], lb = (int)labels[row];
      #pragma unroll
      for (int ni=0;ni<4;ni++){
        int c = nbase + ni*16 + lr;
        xp[(size_t)row*G3 + c] = acc[mi][ni][r] + bi[c]
            + mk*Tans[a*G3+c] + Tcae[ca*G3+c] + mk*Tlab[lb*G3+c];
      }
    }
  }
}

// ---------------- h1 = relu(pred@l1W.T + b) (bf16 out) ----------------
__global__ __launch_bounds__(256) void gemm_l1(const bf16* __restrict__ pred,
        const bf16* __restrict__ Wb, const float* __restrict__ bias,
        bf16* __restrict__ h1){
  MFMA_CORE(pred, PP, Wb, PP, PP)
  #pragma unroll
  for (int mi=0;mi<4;mi++){
    #pragma unroll
    for (int ni=0;ni<4;ni++){
      int c = nbase + ni*16 + lr;
      float bia = bias[c];
      #pragma unroll
      for (int r=0;r<4;r++){
        int row = mbase + mi*16 + (lane>>4)*4 + r;
        h1[(size_t)row*PP + c] = __float2bfloat16(fmaxf(acc[mi][ni][r] + bia, 0.f));
      }
    }
  }
}

// ---------------- h2 tile + fused (h2+pred)@outW partial into logits ----------------
__global__ __launch_bounds__(256) void gemm_l2_logits(const bf16* __restrict__ h1,
        const bf16* __restrict__ Wb, const float* __restrict__ bias,
        const bf16* __restrict__ pred, const float* __restrict__ outW,
        float* __restrict__ logits){
  MFMA_CORE(h1, PP, Wb, PP, PP)
  #pragma unroll
  for (int mi=0;mi<4;mi++){
    #pragma unroll
    for (int r=0;r<4;r++){
      int row = mbase + mi*16 + (lane>>4)*4 + r;
      float p = 0.f;
      #pragma unroll
      for (int ni=0;ni<4;ni++){
        int c = nbase + ni*16 + lr;
        float h2v = fmaxf(acc[mi][ni][r] + bias[c], 0.f);
        p += (h2v + __bfloat162float(pred[(size_t)row*PP + c])) * outW[c];
      }
      p += __shfl_xor(p,1);
      p += __shfl_xor(p,2);
      p += __shfl_xor(p,4);
      p += __shfl_xor(p,8);
      if (lr == 0) atomicAdd(&logits[row], p);
    }
  }
}

// ---------------- GRU scan: one block per batch element ----------------
// 768 threads: 2 threads per output (k split in half, 64 FMAs each, 4 partial
// accumulators -> dep chain ~16 FMAs), lane-pair shfl_xor combine.
__global__ __launch_bounds__(768, 1) void gru_scan(const float* __restrict__ xp,
        const float* __restrict__ Wh, const float* __restrict__ bh,
        bf16* __restrict__ pred){
  __shared__ float hs[HH];
  __shared__ float gh[G3];
  int b = blockIdx.x;
  int tid = threadIdx.x;       // 0..767
  int o = tid >> 1;            // output 0..383
  int half = tid & 1;          // k-half
  int kbase = half * 64;
  if (tid < HH) hs[tid] = 0.f;
  // 64 weights (16 float4) for this (o, half)
  float4 w[16];
  const float4* wr = (const float4*)(Wh + (size_t)o*HH + kbase);
  #pragma unroll
  for (int i=0;i<16;i++) w[i] = wr[i];
  float bhv = half ? 0.f : bh[o];
  // prefetch t=0 x-row gates
  float xr=0.f, xz=0.f, xn=0.f;
  if (tid < HH){
    const float* xrow = xp + (size_t)b*G3;
    xr = xrow[tid]; xz = xrow[HH+tid]; xn = xrow[2*HH+tid];
  }
  __syncthreads();
  for (int t=0;t<SS;t++){
    float nxr=0.f, nxz=0.f, nxn=0.f;
    if (tid < HH && t+1 < SS){
      const float* xrow = xp + (size_t)((t+1)*BB + b)*G3;
      nxr = xrow[tid]; nxz = xrow[HH+tid]; nxn = xrow[2*HH+tid];
    }
    // half-dot with 4 independent accumulator chains
    float a0 = bhv, a1 = 0.f, a2 = 0.f, a3 = 0.f;
    #pragma unroll
    for (int i=0;i<4;i++){
      float4 w0 = w[i],    w1 = w[i+4],  w2 = w[i+8],  w3 = w[i+12];
      float4 h0 = *(const float4*)(&hs[kbase + i*4]);
      float4 h1 = *(const float4*)(&hs[kbase + 16 + i*4]);
      float4 h2 = *(const float4*)(&hs[kbase + 32 + i*4]);
      float4 h3 = *(const float4*)(&hs[kbase + 48 + i*4]);
      a0 += w0.x*h0.x + w0.y*h0.y + w0.z*h0.z + w0.w*h0.w;
      a1 += w1.x*h1.x + w1.y*h1.y + w1.z*h1.z + w1.w*h1.w;
      a2 += w2.x*h2.x + w2.y*h2.y + w2.z*h2.z + w2.w*h2.w;
      a3 += w3.x*h3.x + w3.y*h3.y + w3.z*h3.z + w3.w*h3.w;
    }
    float sum = (a0+a1)+(a2+a3);
    sum += __shfl_xor(sum, 1);          // combine the two k-halves (lane pair)
    if (!half) gh[o] = sum;
    __syncthreads();
    if (tid < HH){
      float hprev = hs[tid];
      float r = sigf(xr + gh[tid]);
      float z = sigf(xz + gh[HH+tid]);
      float n = tanhf(xn + r*gh[2*HH+tid]);
      float hnew = (1.f - z)*n + z*hprev;
      pred[(size_t)(t*BB + b)*PP + 256 + tid] = __float2bfloat16(hprev);
      hs[tid] = hnew;
    }
    __syncthreads();
    xr=nxr; xz=nxz; xn=nxn;
  }
}

// ---------------- loss + probs ----------------
__global__ __launch_bounds__(256) void loss_probs_k(const float* __restrict__ logits,
        const float* __restrict__ labels, const float* __restrict__ tm,
        const float* __restrict__ vm, const float* __restrict__ lm,
        const float* __restrict__ out_b, float* __restrict__ out,
        float* __restrict__ lacc){
  int i = blockIdx.x*256 + threadIdx.x;
  float x = logits[i] + out_b[0];
  float lb = labels[i];
  float mk = tm[i]*vm[i]*lm[i];
  float sp = fmaxf(x,0.f) + log1pf(expf(-fabsf(x)));
  float pe = (sp - x*lb)*mk;
  out[1+i] = sigf(x);
  float v0 = pe, v1 = mk;
  for (int o=32;o>0;o>>=1){ v0 += __shfl_down(v0,o); v1 += __shfl_down(v1,o); }
  if ((threadIdx.x & 63)==0){ atomicAdd(&lacc[0], v0); atomicAdd(&lacc[1], v1); }
}

__global__ void finalize_k(const float* __restrict__ lacc, float* __restrict__ out){
  out[0] = lacc[0]/lacc[1];
}

// ---------------- launch ----------------
extern "C" void kernel_launch(void* const* d_in, const int* in_sizes, int n_in,
                              void* d_out, int out_size, void* d_ws, size_t ws_size,
                              hipStream_t stream) {
  const float* q_emb   = (const float*)d_in[0];
  const float* s_emb   = (const float*)d_in[1];
  const float* ans_emb = (const float*)d_in[2];
  const float* lab_emb = (const float*)d_in[3];
  const float* gru_Wi  = (const float*)d_in[4];
  const float* gru_Wh  = (const float*)d_in[5];
  const float* gru_bi  = (const float*)d_in[6];
  const float* gru_bh  = (const float*)d_in[7];
  const float* s2s_W   = (const float*)d_in[8];
  const float* s2s_b   = (const float*)d_in[9];
  const float* s2q_W   = (const float*)d_in[10];
  const float* s2q_b   = (const float*)d_in[11];
  const float* q2q_W   = (const float*)d_in[12];
  const float* q2q_b   = (const float*)d_in[13];
  const float* q2s_W   = (const float*)d_in[14];
  const float* q2s_b   = (const float*)d_in[15];
  const float* l1_W    = (const float*)d_in[16];
  const float* l1_b    = (const float*)d_in[17];
  const float* l2_W    = (const float*)d_in[18];
  const float* l2_b    = (const float*)d_in[19];
  const float* out_W   = (const float*)d_in[20];
  const float* out_b   = (const float*)d_in[21];
  const float* tm      = (const float*)d_in[22];
  const float* vm      = (const float*)d_in[23];
  const float* lm      = (const float*)d_in[24];
  const float* smask   = (const float*)d_in[25];
  const float* q_mask  = (const float*)d_in[26];
  const float* labels  = (const float*)d_in[27];
  const int*   ans     = (const int*)d_in[28];
  const int*   cans    = (const int*)d_in[29];
  const int*   sub_ids = (const int*)d_in[30];
  const int*   q_ids   = (const int*)d_in[31];
  const int*   q_map   = (const int*)d_in[32];

  // ---- workspace layout (byte offsets, 256B-aligned) ----
  char* wsb = (char*)d_ws;
  size_t off = 0;
  auto alloc = [&](size_t bytes) -> char* {
    char* p = wsb + off;
    off += (bytes + 255) & ~(size_t)255;
    return p;
  };
  float* sums   = (float*)alloc(51200*4);        // [Ns,D]
  float* cnts   = (float*)alloc(400*4);
  float* subj1  = (float*)alloc(51200*4);        // [Ns,D] f32
  float* Tans   = (float*)alloc(4*G3*4);
  float* Tcae   = (float*)alloc(4*G3*4);
  float* Tlab   = (float*)alloc(2*G3*4);
  float* lacc   = (float*)alloc(2*4);
  float* logits = (float*)alloc((size_t)SB*4);
  bf16*  l1Wb   = (bf16*) alloc((size_t)512*512*2);
  bf16*  l2Wb   = (bf16*) alloc((size_t)512*512*2);
  bf16*  WiB    = (bf16*) alloc((size_t)384*256*2);
  bf16*  q1     = (bf16*) alloc((size_t)NQ*DD*2);        // 7.68 MB
  bf16*  pred   = (bf16*) alloc((size_t)SB*PP*2);        // 52.4 MB
  char*  xh     = alloc((size_t)SB*G3*4);                // 78.6 MB: xp f32, then h1 bf16
  float* xp     = (float*)xh;
  bf16*  h1     = (bf16*)xh;   // aliased: xp dead after gru_scan
  float* out    = (float*)d_out;

  hipMemsetAsync(sums, 0, (51200+400)*sizeof(float), stream);
  hipMemsetAsync(lacc, 0, 2*sizeof(float), stream);
  hipMemsetAsync(logits, 0, (size_t)SB*sizeof(float), stream);

  tables_k<<<dim3(3), dim3(128), 0, stream>>>(ans_emb, lab_emb, gru_Wi, Tans, Tcae, Tlab);
  conv_w_k<<<dim3(1024), dim3(256), 0, stream>>>(l1_W, l2_W, gru_Wi, l1Wb, l2Wb, WiB);
  q2s_scatter<<<dim3(NQ/QPB), dim3(128), 0, stream>>>(q_emb, q2s_W, q2s_b, q_map, sums, cnts);
  subjects1_k<<<dim3(NS), dim3(128), 0, stream>>>(s_emb, s2s_W, s2s_b, sums, cnts, subj1);
  questions1_k<<<dim3(NQ/QPB), dim3(128), 0, stream>>>(q_emb, subj1, q_map, q_mask,
                                                       s2q_W, s2q_b, q2q_W, q2q_b, q1);
  assemble_k<<<dim3(SB), dim3(128), 0, stream>>>(q1, subj1, ans_emb, cans, sub_ids, smask, q_ids, pred);
  // grid: x = m-blocks (fast-varying -> W panel stays L2-hot), y = n-blocks
  gemm_xp<<<dim3(400,3), dim3(256), 0, stream>>>(pred, WiB, gru_bi, Tans, Tcae, Tlab,
                                                 tm, vm, lm, ans, cans, labels, xp);
  gru_scan<<<dim3(BB), dim3(768), 0, stream>>>(xp, gru_Wh, gru_bh, pred);
  gemm_l1<<<dim3(400,4), dim3(256), 0, stream>>>(pred, l1Wb, l1_b, h1);
  gemm_l2_logits<<<dim3(400,4), dim3(256), 0, stream>>>(h1, l2Wb, l2_b, pred, out_W, logits);
  loss_probs_k<<<dim3(SB/256), dim3(256), 0, stream>>>(logits, labels, tm, vm, lm, out_b, out, lacc);
  finalize_k<<<dim3(1), dim3(1), 0, stream>>>(lacc, out);
}

// Round 6
// 1025.865 us; speedup vs baseline: 1.0039x; 1.0039x over previous
//
#include <hip/hip_runtime.h>
#include <hip/hip_bf16.h>
#include <math.h>

#define NQ 30000
#define NS 400
#define DD 128
#define HH 128
#define SS 200
#define BB 256
#define MSq 4
#define MBs 4
#define PP 512
#define SB (SS*BB)      // 51200
#define G3 384          // 3*H
#define QPB 16

typedef __hip_bfloat16 bf16;
typedef __attribute__((ext_vector_type(8))) short bf16x8;
typedef __attribute__((ext_vector_type(4))) float f32x4;

__device__ __forceinline__ float sigf(float x){ return 1.0f/(1.0f+expf(-x)); }
__device__ __forceinline__ float sigf2(float x){ return 1.0f/(1.0f+__expf(-x)); }
__device__ __forceinline__ float tanhf2(float x){ return 1.0f - 2.0f/(__expf(2.0f*x)+1.0f); }
__device__ __forceinline__ float bf2f(unsigned short u){
  unsigned int x = ((unsigned int)u)<<16;
  return __uint_as_float(x);
}

// ---------------- tables: T_ans = ans_emb @ Wi[:,0:128].T etc ----------------
__global__ __launch_bounds__(128) void tables_k(const float* __restrict__ ans_emb,
        const float* __restrict__ label_emb, const float* __restrict__ Wi,
        float* __restrict__ Tans, float* __restrict__ Tcae, float* __restrict__ Tlab){
  int j = blockIdx.x*128 + threadIdx.x;
  if (j >= G3) return;
  const float* wr = Wi + (size_t)j*640;
  for (int a=0;a<4;a++){
    float acc=0.f;
    for (int k=0;k<DD;k++) acc += ans_emb[a*DD+k]*wr[k];
    Tans[a*G3+j]=acc;
  }
  for (int a=0;a<4;a++){
    float acc=0.f;
    for (int k=0;k<DD;k++) acc += ans_emb[a*DD+k]*wr[128+k];
    Tcae[a*G3+j]=acc;
  }
  for (int l=0;l<2;l++){
    float acc=0.f;
    for (int k=0;k<DD;k++) acc += label_emb[l*DD+k]*wr[256+k];
    Tlab[l*G3+j]=acc;
  }
}

// ---------------- weight convert: f32 -> bf16 ----------------
__global__ __launch_bounds__(256) void conv_w_k(const float* __restrict__ l1W,
        const float* __restrict__ l2W, const float* __restrict__ Wi,
        bf16* __restrict__ l1Wb, bf16* __restrict__ l2Wb, bf16* __restrict__ WiB){
  int i = blockIdx.x*256 + threadIdx.x;
  if (i < 512*512){
    l1Wb[i] = __float2bfloat16(l1W[i]);
    l2Wb[i] = __float2bfloat16(l2W[i]);
  }
  if (i < 384*256){
    int j = i >> 8, k = i & 255;
    WiB[i] = __float2bfloat16(Wi[j*640 + 384 + k]);
  }
}

// ---------------- q2s projection + scatter to subject sums ----------------
__global__ __launch_bounds__(128) void q2s_scatter(const float* __restrict__ q_emb,
        const float* __restrict__ W, const float* __restrict__ bias,
        const int* __restrict__ q_map, float* __restrict__ sums, float* __restrict__ cnts){
  __shared__ float qe[QPB][DD];
  int q0 = blockIdx.x*QPB;
  int tid = threadIdx.x;
  for (int r=0;r<QPB;r++) qe[r][tid] = q_emb[(size_t)(q0+r)*DD + tid];
  __syncthreads();
  float acc[QPB];
  #pragma unroll
  for (int r=0;r<QPB;r++) acc[r] = bias[tid];
  const float4* wr = (const float4*)(W + (size_t)tid*DD);
  #pragma unroll 4
  for (int k4=0;k4<DD/4;k4++){
    float4 w = wr[k4];
    #pragma unroll
    for (int r=0;r<QPB;r++){
      acc[r] += w.x*qe[r][k4*4] + w.y*qe[r][k4*4+1] + w.z*qe[r][k4*4+2] + w.w*qe[r][k4*4+3];
    }
  }
  for (int r=0;r<QPB;r++){
    int q = q0+r;
    #pragma unroll
    for (int m=0;m<MSq;m++){
      int s = q_map[q*MSq+m];
      atomicAdd(&sums[(size_t)s*DD + tid], acc[r]);
      if (tid==0) atomicAdd(&cnts[s], 1.0f);
    }
  }
}

// ---------------- subjects_1 ----------------
__global__ __launch_bounds__(128) void subjects1_k(const float* __restrict__ s_emb,
        const float* __restrict__ W, const float* __restrict__ bias,
        const float* __restrict__ sums, const float* __restrict__ cnts,
        float* __restrict__ out){
  __shared__ float se[DD];
  int s = blockIdx.x; int tid = threadIdx.x;
  se[tid] = s_emb[(size_t)s*DD+tid];
  __syncthreads();
  float acc = bias[tid];
  const float4* wr = (const float4*)(W + (size_t)tid*DD);
  for (int k4=0;k4<DD/4;k4++){
    float4 w = wr[k4];
    acc += w.x*se[k4*4] + w.y*se[k4*4+1] + w.z*se[k4*4+2] + w.w*se[k4*4+3];
  }
  float c = cnts[s];
  float v = 0.f;
  if (c > 0.f) v = tanhf(sums[(size_t)s*DD+tid]/fmaxf(c,1.f) + acc);
  out[(size_t)s*DD+tid] = v;
}

// ---------------- questions_1 (bf16 out) ----------------
__global__ __launch_bounds__(128) void questions1_k(const float* __restrict__ q_emb,
        const float* __restrict__ subj1, const int* __restrict__ q_map,
        const float* __restrict__ q_mask,
        const float* __restrict__ s2qW, const float* __restrict__ s2qb,
        const float* __restrict__ q2qW, const float* __restrict__ q2qb,
        bf16* __restrict__ q1out){
  __shared__ float qe[QPB][DD];
  __shared__ float nq[QPB][DD];
  int q0 = blockIdx.x*QPB; int tid = threadIdx.x;
  for (int r=0;r<QPB;r++){
    int q = q0+r;
    qe[r][tid] = q_emb[(size_t)q*DD+tid];
    float sum=0.f, wsum=0.f;
    #pragma unroll
    for (int m=0;m<MSq;m++){
      float w = q_mask[q*MSq+m];
      sum += subj1[(size_t)q_map[q*MSq+m]*DD + tid]*w;
      wsum += w;
    }
    nq[r][tid] = sum / wsum;
  }
  __syncthreads();
  float acc[QPB];
  #pragma unroll
  for (int r=0;r<QPB;r++) acc[r] = s2qb[tid]+q2qb[tid];
  const float4* w1 = (const float4*)(s2qW + (size_t)tid*DD);
  const float4* w2 = (const float4*)(q2qW + (size_t)tid*DD);
  #pragma unroll 2
  for (int k4=0;k4<DD/4;k4++){
    float4 a = w1[k4]; float4 b = w2[k4];
    #pragma unroll
    for (int r=0;r<QPB;r++){
      acc[r] += a.x*nq[r][k4*4] + a.y*nq[r][k4*4+1] + a.z*nq[r][k4*4+2] + a.w*nq[r][k4*4+3]
              + b.x*qe[r][k4*4] + b.y*qe[r][k4*4+1] + b.z*qe[r][k4*4+2] + b.w*qe[r][k4*4+3];
    }
  }
  for (int r=0;r<QPB;r++) q1out[(size_t)(q0+r)*DD+tid] = __float2bfloat16(tanhf(acc[r]));
}

// ---------------- assemble pred_input cols 0:256 and 384:512 (bf16) ----------------
__global__ __launch_bounds__(128) void assemble_k(const bf16* __restrict__ q1,
        const float* __restrict__ subj1, const float* __restrict__ ans_emb,
        const int* __restrict__ cans, const int* __restrict__ sub_ids,
        const float* __restrict__ sub_mask, const int* __restrict__ q_ids,
        bf16* __restrict__ pred){
  int i = blockIdx.x; int d = threadIdx.x;
  size_t base = (size_t)i*PP;
  pred[base + d] = q1[(size_t)q_ids[i]*DD + d];
  float s = 0.f;
  #pragma unroll
  for (int m=0;m<MBs;m++)
    s += subj1[(size_t)sub_ids[i*MBs+m]*DD+d]*sub_mask[i*MBs+m];
  pred[base+128+d] = __float2bfloat16(s);
  pred[base+384+d] = __float2bfloat16(ans_emb[(size_t)cans[i]*DD + d]);
}

// ======== MFMA GEMM core (unchanged, verified) ========
#define MFMA_CORE(A_, lda_, B_, ldb_, K_) \
  int lane = threadIdx.x & 63; int wid = threadIdx.x >> 6; \
  int wy = wid >> 1, wx = wid & 1; \
  int mbase = blockIdx.x*128 + wy*64; \
  int nbase = blockIdx.y*128 + wx*64; \
  int lr = lane & 15, kg = (lane >> 4) * 8; \
  f32x4 acc[4][4]; \
  _Pragma("unroll") for (int i=0;i<4;i++) _Pragma("unroll") for (int j=0;j<4;j++) acc[i][j] = (f32x4){0.f,0.f,0.f,0.f}; \
  for (int k=0; k<(K_); k+=32){ \
    bf16x8 af[4], bfr[4]; \
    _Pragma("unroll") for (int mi=0;mi<4;mi++) \
      af[mi] = *(const bf16x8*)((A_) + (size_t)(mbase+mi*16+lr)*(lda_) + k + kg); \
    _Pragma("unroll") for (int ni=0;ni<4;ni++) \
      bfr[ni] = *(const bf16x8*)((B_) + (size_t)(nbase+ni*16+lr)*(ldb_) + k + kg); \
    _Pragma("unroll") for (int mi=0;mi<4;mi++) \
      _Pragma("unroll") for (int ni=0;ni<4;ni++) \
        acc[mi][ni] = __builtin_amdgcn_mfma_f32_16x16x32_bf16(af[mi], bfr[ni], acc[mi][ni], 0, 0, 0); \
  }

// ---------------- xp = pred[:,0:256]@WiB.T + tables + bi ----------------
__global__ __launch_bounds__(256) void gemm_xp(const bf16* __restrict__ pred,
        const bf16* __restrict__ WiB, const float* __restrict__ bi,
        const float* __restrict__ Tans, const float* __restrict__ Tcae,
        const float* __restrict__ Tlab,
        const float* __restrict__ tm, const float* __restrict__ vm,
        const float* __restrict__ lm,
        const int* __restrict__ ans, const int* __restrict__ cans,
        const float* __restrict__ labels, float* __restrict__ xp){
  MFMA_CORE(pred, PP, WiB, 256, 256)
  #pragma unroll
  for (int mi=0;mi<4;mi++){
    #pragma unroll
    for (int r=0;r<4;r++){
      int row = mbase + mi*16 + (lane>>4)*4 + r;
      float mk = tm[row]*vm[row]*lm[row];
      int a = ans[row], ca = cans[row], lb = (int)labels[row];
      #pragma unroll
      for (int ni=0;ni<4;ni++){
        int c = nbase + ni*16 + lr;
        xp[(size_t)row*G3 + c] = acc[mi][ni][r] + bi[c]
            + mk*Tans[a*G3+c] + Tcae[ca*G3+c] + mk*Tlab[lb*G3+c];
      }
    }
  }
}

// ---------------- h1 = relu(pred@l1W.T + b) (bf16 out) ----------------
__global__ __launch_bounds__(256) void gemm_l1(const bf16* __restrict__ pred,
        const bf16* __restrict__ Wb, const float* __restrict__ bias,
        bf16* __restrict__ h1){
  MFMA_CORE(pred, PP, Wb, PP, PP)
  #pragma unroll
  for (int mi=0;mi<4;mi++){
    #pragma unroll
    for (int ni=0;ni<4;ni++){
      int c = nbase + ni*16 + lr;
      float bia = bias[c];
      #pragma unroll
      for (int r=0;r<4;r++){
        int row = mbase + mi*16 + (lane>>4)*4 + r;
        h1[(size_t)row*PP + c] = __float2bfloat16(fmaxf(acc[mi][ni][r] + bia, 0.f));
      }
    }
  }
}

// ---------------- h2 tile + fused (h2+pred)@outW partial into logits ----------------
__global__ __launch_bounds__(256) void gemm_l2_logits(const bf16* __restrict__ h1,
        const bf16* __restrict__ Wb, const float* __restrict__ bias,
        const bf16* __restrict__ pred, const float* __restrict__ outW,
        float* __restrict__ logits){
  MFMA_CORE(h1, PP, Wb, PP, PP)
  #pragma unroll
  for (int mi=0;mi<4;mi++){
    #pragma unroll
    for (int r=0;r<4;r++){
      int row = mbase + mi*16 + (lane>>4)*4 + r;
      float p = 0.f;
      #pragma unroll
      for (int ni=0;ni<4;ni++){
        int c = nbase + ni*16 + lr;
        float h2v = fmaxf(acc[mi][ni][r] + bias[c], 0.f);
        p += (h2v + __bfloat162float(pred[(size_t)row*PP + c])) * outW[c];
      }
      p += __shfl_xor(p,1);
      p += __shfl_xor(p,2);
      p += __shfl_xor(p,4);
      p += __shfl_xor(p,8);
      if (lr == 0) atomicAdd(&logits[row], p);
    }
  }
}

// ================= MFMA GRU scan =================
// 16 blocks x 16 batch rows. 512 thr = 8 waves; wave w owns gate-triplet rows
// for d in [16w,16w+16): B-frags (Wh, permuted by gate) live in VGPRs for the
// whole scan. h state f32 in gate-owner lanes' registers; bf16 copy transits a
// 4KB XOR-swizzled LDS tile for the next step's A-fragments (G4 swizzle;
// write & read use the identical XOR -> rule 21 satisfied).
__global__ __launch_bounds__(512, 1) void gru_scan_mfma(const float* __restrict__ xp,
        const float* __restrict__ Wh, const float* __restrict__ bh,
        bf16* __restrict__ pred){
  __shared__ __align__(16) char hbf[4096];   // bf16 h[16 rows][128 d], swizzled
  const int tid  = threadIdx.x;
  const int lane = tid & 63;
  const int w    = tid >> 6;        // wave 0..7
  const int lr   = lane & 15;       // d-within-wave / A-row (batch)
  const int lg   = lane >> 4;       // 0..3: k-group / batch-group
  const int d    = w*16 + lr;       // h-dim this lane owns for gates
  const int bg0  = blockIdx.x * 16; // global batch base

  // ---- preload Wh fragments (bf16) : wfG[kk] for gate G, k-tile kk ----
  union U8 { bf16x8 v; unsigned short s[8]; };
  bf16x8 wf0[4], wf1[4], wf2[4];
  #pragma unroll
  for (int kk=0; kk<4; kk++){
    #pragma unroll
    for (int g=0; g<3; g++){
      const float* src = Wh + (size_t)(g*HH + d)*HH + kk*32 + lg*8;
      U8 u;
      #pragma unroll
      for (int j=0;j<8;j++){
        bf16 bv = __float2bfloat16(src[j]);
        u.s[j] = reinterpret_cast<unsigned short&>(bv);
      }
      if (g==0) wf0[kk]=u.v; else if (g==1) wf1[kk]=u.v; else wf2[kk]=u.v;
    }
  }
  const float bh0 = bh[d], bh1 = bh[HH+d], bh2 = bh[2*HH+d];

  float h[4] = {0.f,0.f,0.f,0.f};           // h for batch rows lg*4+q
  ((unsigned long long*)hbf)[tid] = 0ULL;   // zero the 4KB tile

  float xA[12], xB[12];
#define LOADX(X_, t_) do{ if ((t_) < SS){ \
    _Pragma("unroll") for (int q=0;q<4;q++){ \
      const float* xr_ = xp + ((size_t)(t_)*BB + bg0 + lg*4 + q)*G3 + d; \
      X_[q*3+0] = xr_[0]; X_[q*3+1] = xr_[HH]; X_[q*3+2] = xr_[2*HH]; \
    } } }while(0)

  LOADX(xA, 0);
  LOADX(xB, 1);
  __syncthreads();

#define GSTEP(t_, X_) { \
    f32x4 ac0 = (f32x4){0.f,0.f,0.f,0.f}, ac1 = ac0, ac2 = ac0; \
    _Pragma("unroll") for (int kk=0; kk<4; kk++){ \
      bf16x8 a = *(const bf16x8*)(hbf + lr*256 + ((kk*64 + lg*16) ^ ((lr&7)<<4))); \
      ac0 = __builtin_amdgcn_mfma_f32_16x16x32_bf16(a, wf0[kk], ac0, 0,0,0); \
      ac1 = __builtin_amdgcn_mfma_f32_16x16x32_bf16(a, wf1[kk], ac1, 0,0,0); \
      ac2 = __builtin_amdgcn_mfma_f32_16x16x32_bf16(a, wf2[kk], ac2, 0,0,0); \
    } \
    float hold[4]; \
    _Pragma("unroll") for (int q=0;q<4;q++){ \
      float r  = sigf2(X_[q*3+0] + ac0[q] + bh0); \
      float zg = sigf2(X_[q*3+1] + ac1[q] + bh1); \
      float n  = tanhf2(X_[q*3+2] + r*(ac2[q] + bh2)); \
      hold[q] = h[q]; \
      h[q] = (1.f - zg)*n + zg*h[q]; \
    } \
    _Pragma("unroll") for (int q=0;q<4;q++) \
      pred[((size_t)(t_)*BB + bg0 + lg*4 + q)*PP + 256 + d] = __float2bfloat16(hold[q]); \
    __syncthreads();   /* all waves' A-frag reads done before overwrite */ \
    _Pragma("unroll") for (int q=0;q<4;q++){ \
      int B_ = lg*4 + q; \
      *(bf16*)(hbf + B_*256 + ((2*d) ^ ((B_&7)<<4))) = __float2bfloat16(h[q]); \
    } \
    LOADX(X_, (t_)+2); \
    __syncthreads();   /* new h visible for next step */ \
  }

  for (int t=0; t<SS; t+=2){
    GSTEP(t, xA)
    GSTEP(t+1, xB)
  }
#undef GSTEP
#undef LOADX
}

// ---------------- loss + probs ----------------
__global__ __launch_bounds__(256) void loss_probs_k(const float* __restrict__ logits,
        const float* __restrict__ labels, const float* __restrict__ tm,
        const float* __restrict__ vm, const float* __restrict__ lm,
        const float* __restrict__ out_b, float* __restrict__ out,
        float* __restrict__ lacc){
  int i = blockIdx.x*256 + threadIdx.x;
  float x = logits[i] + out_b[0];
  float lb = labels[i];
  float mk = tm[i]*vm[i]*lm[i];
  float sp = fmaxf(x,0.f) + log1pf(expf(-fabsf(x)));
  float pe = (sp - x*lb)*mk;
  out[1+i] = sigf(x);
  float v0 = pe, v1 = mk;
  for (int o=32;o>0;o>>=1){ v0 += __shfl_down(v0,o); v1 += __shfl_down(v1,o); }
  if ((threadIdx.x & 63)==0){ atomicAdd(&lacc[0], v0); atomicAdd(&lacc[1], v1); }
}

__global__ void finalize_k(const float* __restrict__ lacc, float* __restrict__ out){
  out[0] = lacc[0]/lacc[1];
}

// ---------------- launch ----------------
extern "C" void kernel_launch(void* const* d_in, const int* in_sizes, int n_in,
                              void* d_out, int out_size, void* d_ws, size_t ws_size,
                              hipStream_t stream) {
  const float* q_emb   = (const float*)d_in[0];
  const float* s_emb   = (const float*)d_in[1];
  const float* ans_emb = (const float*)d_in[2];
  const float* lab_emb = (const float*)d_in[3];
  const float* gru_Wi  = (const float*)d_in[4];
  const float* gru_Wh  = (const float*)d_in[5];
  const float* gru_bi  = (const float*)d_in[6];
  const float* gru_bh  = (const float*)d_in[7];
  const float* s2s_W   = (const float*)d_in[8];
  const float* s2s_b   = (const float*)d_in[9];
  const float* s2q_W   = (const float*)d_in[10];
  const float* s2q_b   = (const float*)d_in[11];
  const float* q2q_W   = (const float*)d_in[12];
  const float* q2q_b   = (const float*)d_in[13];
  const float* q2s_W   = (const float*)d_in[14];
  const float* q2s_b   = (const float*)d_in[15];
  const float* l1_W    = (const float*)d_in[16];
  const float* l1_b    = (const float*)d_in[17];
  const float* l2_W    = (const float*)d_in[18];
  const float* l2_b    = (const float*)d_in[19];
  const float* out_W   = (const float*)d_in[20];
  const float* out_b   = (const float*)d_in[21];
  const float* tm      = (const float*)d_in[22];
  const float* vm      = (const float*)d_in[23];
  const float* lm      = (const float*)d_in[24];
  const float* smask   = (const float*)d_in[25];
  const float* q_mask  = (const float*)d_in[26];
  const float* labels  = (const float*)d_in[27];
  const int*   ans     = (const int*)d_in[28];
  const int*   cans    = (const int*)d_in[29];
  const int*   sub_ids = (const int*)d_in[30];
  const int*   q_ids   = (const int*)d_in[31];
  const int*   q_map   = (const int*)d_in[32];

  // ---- workspace layout (byte offsets, 256B-aligned) ----
  char* wsb = (char*)d_ws;
  size_t off = 0;
  auto alloc = [&](size_t bytes) -> char* {
    char* p = wsb + off;
    off += (bytes + 255) & ~(size_t)255;
    return p;
  };
  float* sums   = (float*)alloc(51200*4);        // [Ns,D]
  float* cnts   = (float*)alloc(400*4);
  float* subj1  = (float*)alloc(51200*4);        // [Ns,D] f32
  float* Tans   = (float*)alloc(4*G3*4);
  float* Tcae   = (float*)alloc(4*G3*4);
  float* Tlab   = (float*)alloc(2*G3*4);
  float* lacc   = (float*)alloc(2*4);
  float* logits = (float*)alloc((size_t)SB*4);
  bf16*  l1Wb   = (bf16*) alloc((size_t)512*512*2);
  bf16*  l2Wb   = (bf16*) alloc((size_t)512*512*2);
  bf16*  WiB    = (bf16*) alloc((size_t)384*256*2);
  bf16*  q1     = (bf16*) alloc((size_t)NQ*DD*2);        // 7.68 MB
  bf16*  pred   = (bf16*) alloc((size_t)SB*PP*2);        // 52.4 MB
  char*  xh     = alloc((size_t)SB*G3*4);                // 78.6 MB: xp f32, then h1 bf16
  float* xp     = (float*)xh;
  bf16*  h1     = (bf16*)xh;   // aliased: xp dead after gru_scan
  float* out    = (float*)d_out;

  hipMemsetAsync(sums, 0, (51200+400)*sizeof(float), stream);
  hipMemsetAsync(lacc, 0, 2*sizeof(float), stream);
  hipMemsetAsync(logits, 0, (size_t)SB*sizeof(float), stream);

  tables_k<<<dim3(3), dim3(128), 0, stream>>>(ans_emb, lab_emb, gru_Wi, Tans, Tcae, Tlab);
  conv_w_k<<<dim3(1024), dim3(256), 0, stream>>>(l1_W, l2_W, gru_Wi, l1Wb, l2Wb, WiB);
  q2s_scatter<<<dim3(NQ/QPB), dim3(128), 0, stream>>>(q_emb, q2s_W, q2s_b, q_map, sums, cnts);
  subjects1_k<<<dim3(NS), dim3(128), 0, stream>>>(s_emb, s2s_W, s2s_b, sums, cnts, subj1);
  questions1_k<<<dim3(NQ/QPB), dim3(128), 0, stream>>>(q_emb, subj1, q_map, q_mask,
                                                       s2q_W, s2q_b, q2q_W, q2q_b, q1);
  assemble_k<<<dim3(SB), dim3(128), 0, stream>>>(q1, subj1, ans_emb, cans, sub_ids, smask, q_ids, pred);
  // grid: x = m-blocks (fast-varying -> W panel stays L2-hot), y = n-blocks
  gemm_xp<<<dim3(400,3), dim3(256), 0, stream>>>(pred, WiB, gru_bi, Tans, Tcae, Tlab,
                                                 tm, vm, lm, ans, cans, labels, xp);
  gru_scan_mfma<<<dim3(16), dim3(512), 0, stream>>>(xp, gru_Wh, gru_bh, pred);
  gemm_l1<<<dim3(400,4), dim3(256), 0, stream>>>(pred, l1Wb, l1_b, h1);
  gemm_l2_logits<<<dim3(400,4), dim3(256), 0, stream>>>(h1, l2Wb, l2_b, pred, out_W, logits);
  loss_probs_k<<<dim3(SB/256), dim3(256), 0, stream>>>(logits, labels, tm, vm, lm, out_b, out, lacc);
  finalize_k<<<dim3(1), dim3(1), 0, stream>>>(lacc, out);
}

// Round 7
// 979.118 us; speedup vs baseline: 1.0518x; 1.0477x over previous
//
#include <hip/hip_runtime.h>
#include <hip/hip_bf16.h>
#include <math.h>

#define NQ 30000
#define NS 400
#define DD 128
#define HH 128
#define SS 200
#define BB 256
#define MSq 4
#define MBs 4
#define PP 512
#define SB (SS*BB)      // 51200
#define G3 384          // 3*H
#define QPB 16
#define REPL 8          // q2s atomic replicas

typedef __hip_bfloat16 bf16;
typedef __attribute__((ext_vector_type(8))) short bf16x8;
typedef __attribute__((ext_vector_type(4))) float f32x4;

__device__ __forceinline__ float sigf(float x){ return 1.0f/(1.0f+expf(-x)); }
__device__ __forceinline__ float sigf2(float x){ return 1.0f/(1.0f+__expf(-x)); }
__device__ __forceinline__ float tanhf2(float x){ return 1.0f - 2.0f/(__expf(2.0f*x)+1.0f); }
__device__ __forceinline__ float bf2f(unsigned short u){
  unsigned int x = ((unsigned int)u)<<16;
  return __uint_as_float(x);
}

// ---------------- tables: T_ans = ans_emb @ Wi[:,0:128].T etc ----------------
__global__ __launch_bounds__(128) void tables_k(const float* __restrict__ ans_emb,
        const float* __restrict__ label_emb, const float* __restrict__ Wi,
        float* __restrict__ Tans, float* __restrict__ Tcae, float* __restrict__ Tlab){
  int j = blockIdx.x*128 + threadIdx.x;
  if (j >= G3) return;
  const float* wr = Wi + (size_t)j*640;
  for (int a=0;a<4;a++){
    float acc=0.f;
    for (int k=0;k<DD;k++) acc += ans_emb[a*DD+k]*wr[k];
    Tans[a*G3+j]=acc;
  }
  for (int a=0;a<4;a++){
    float acc=0.f;
    for (int k=0;k<DD;k++) acc += ans_emb[a*DD+k]*wr[128+k];
    Tcae[a*G3+j]=acc;
  }
  for (int l=0;l<2;l++){
    float acc=0.f;
    for (int k=0;k<DD;k++) acc += label_emb[l*DD+k]*wr[256+k];
    Tlab[l*G3+j]=acc;
  }
}

// ---------------- weight convert: f32 -> bf16 ----------------
__global__ __launch_bounds__(256) void conv_w_k(const float* __restrict__ l1W,
        const float* __restrict__ l2W, const float* __restrict__ Wi,
        bf16* __restrict__ l1Wb, bf16* __restrict__ l2Wb, bf16* __restrict__ WiB){
  int i = blockIdx.x*256 + threadIdx.x;
  if (i < 512*512){
    l1Wb[i] = __float2bfloat16(l1W[i]);
    l2Wb[i] = __float2bfloat16(l2W[i]);
  }
  if (i < 384*256){
    int j = i >> 8, k = i & 255;
    WiB[i] = __float2bfloat16(Wi[j*640 + 384 + k]);
  }
}

// ---------------- q2s projection + scatter (8-way replicated atomics) ----------------
__global__ __launch_bounds__(128) void q2s_scatter(const float* __restrict__ q_emb,
        const float* __restrict__ W, const float* __restrict__ bias,
        const int* __restrict__ q_map, float* __restrict__ sums, float* __restrict__ cnts){
  __shared__ float qe[QPB][DD];
  int q0 = blockIdx.x*QPB;
  int tid = threadIdx.x;
  float* S = sums + (size_t)(blockIdx.x & (REPL-1))*51200;
  float* C = cnts + (size_t)(blockIdx.x & (REPL-1))*400;
  for (int r=0;r<QPB;r++) qe[r][tid] = q_emb[(size_t)(q0+r)*DD + tid];
  __syncthreads();
  float acc[QPB];
  #pragma unroll
  for (int r=0;r<QPB;r++) acc[r] = bias[tid];
  const float4* wr = (const float4*)(W + (size_t)tid*DD);
  #pragma unroll 4
  for (int k4=0;k4<DD/4;k4++){
    float4 w = wr[k4];
    #pragma unroll
    for (int r=0;r<QPB;r++){
      acc[r] += w.x*qe[r][k4*4] + w.y*qe[r][k4*4+1] + w.z*qe[r][k4*4+2] + w.w*qe[r][k4*4+3];
    }
  }
  for (int r=0;r<QPB;r++){
    int q = q0+r;
    #pragma unroll
    for (int m=0;m<MSq;m++){
      int s = q_map[q*MSq+m];
      atomicAdd(&S[(size_t)s*DD + tid], acc[r]);
      if (tid==0) atomicAdd(&C[s], 1.0f);
    }
  }
}

// ---------------- subjects_1 (reduces the replicas) ----------------
__global__ __launch_bounds__(128) void subjects1_k(const float* __restrict__ s_emb,
        const float* __restrict__ W, const float* __restrict__ bias,
        const float* __restrict__ sums, const float* __restrict__ cnts,
        float* __restrict__ out){
  __shared__ float se[DD];
  int s = blockIdx.x; int tid = threadIdx.x;
  se[tid] = s_emb[(size_t)s*DD+tid];
  __syncthreads();
  float acc = bias[tid];
  const float4* wr = (const float4*)(W + (size_t)tid*DD);
  for (int k4=0;k4<DD/4;k4++){
    float4 w = wr[k4];
    acc += w.x*se[k4*4] + w.y*se[k4*4+1] + w.z*se[k4*4+2] + w.w*se[k4*4+3];
  }
  float c = 0.f, sm = 0.f;
  #pragma unroll
  for (int r=0;r<REPL;r++){
    c  += cnts[r*400 + s];
    sm += sums[(size_t)r*51200 + (size_t)s*DD + tid];
  }
  float v = 0.f;
  if (c > 0.f) v = tanhf(sm/fmaxf(c,1.f) + acc);
  out[(size_t)s*DD+tid] = v;
}

// ---------------- questions_1 (bf16 out) ----------------
__global__ __launch_bounds__(128) void questions1_k(const float* __restrict__ q_emb,
        const float* __restrict__ subj1, const int* __restrict__ q_map,
        const float* __restrict__ q_mask,
        const float* __restrict__ s2qW, const float* __restrict__ s2qb,
        const float* __restrict__ q2qW, const float* __restrict__ q2qb,
        bf16* __restrict__ q1out){
  __shared__ float qe[QPB][DD];
  __shared__ float nq[QPB][DD];
  int q0 = blockIdx.x*QPB; int tid = threadIdx.x;
  for (int r=0;r<QPB;r++){
    int q = q0+r;
    qe[r][tid] = q_emb[(size_t)q*DD+tid];
    float sum=0.f, wsum=0.f;
    #pragma unroll
    for (int m=0;m<MSq;m++){
      float w = q_mask[q*MSq+m];
      sum += subj1[(size_t)q_map[q*MSq+m]*DD + tid]*w;
      wsum += w;
    }
    nq[r][tid] = sum / wsum;
  }
  __syncthreads();
  float acc[QPB];
  #pragma unroll
  for (int r=0;r<QPB;r++) acc[r] = s2qb[tid]+q2qb[tid];
  const float4* w1 = (const float4*)(s2qW + (size_t)tid*DD);
  const float4* w2 = (const float4*)(q2qW + (size_t)tid*DD);
  #pragma unroll 2
  for (int k4=0;k4<DD/4;k4++){
    float4 a = w1[k4]; float4 b = w2[k4];
    #pragma unroll
    for (int r=0;r<QPB;r++){
      acc[r] += a.x*nq[r][k4*4] + a.y*nq[r][k4*4+1] + a.z*nq[r][k4*4+2] + a.w*nq[r][k4*4+3]
              + b.x*qe[r][k4*4] + b.y*qe[r][k4*4+1] + b.z*qe[r][k4*4+2] + b.w*qe[r][k4*4+3];
    }
  }
  for (int r=0;r<QPB;r++) q1out[(size_t)(q0+r)*DD+tid] = __float2bfloat16(tanhf(acc[r]));
}

// ---------------- assemble pred_input cols 0:256 and 384:512 (bf16) ----------------
__global__ __launch_bounds__(128) void assemble_k(const bf16* __restrict__ q1,
        const float* __restrict__ subj1, const float* __restrict__ ans_emb,
        const int* __restrict__ cans, const int* __restrict__ sub_ids,
        const float* __restrict__ sub_mask, const int* __restrict__ q_ids,
        bf16* __restrict__ pred){
  int i = blockIdx.x; int d = threadIdx.x;
  size_t base = (size_t)i*PP;
  pred[base + d] = q1[(size_t)q_ids[i]*DD + d];
  float s = 0.f;
  #pragma unroll
  for (int m=0;m<MBs;m++)
    s += subj1[(size_t)sub_ids[i*MBs+m]*DD+d]*sub_mask[i*MBs+m];
  pred[base+128+d] = __float2bfloat16(s);
  pred[base+384+d] = __float2bfloat16(ans_emb[(size_t)cans[i]*DD + d]);
}

// ======== MFMA GEMM core (unchanged, verified) ========
#define MFMA_CORE(A_, lda_, B_, ldb_, K_) \
  int lane = threadIdx.x & 63; int wid = threadIdx.x >> 6; \
  int wy = wid >> 1, wx = wid & 1; \
  int mbase = blockIdx.x*128 + wy*64; \
  int nbase = blockIdx.y*128 + wx*64; \
  int lr = lane & 15, kg = (lane >> 4) * 8; \
  f32x4 acc[4][4]; \
  _Pragma("unroll") for (int i=0;i<4;i++) _Pragma("unroll") for (int j=0;j<4;j++) acc[i][j] = (f32x4){0.f,0.f,0.f,0.f}; \
  for (int k=0; k<(K_); k+=32){ \
    bf16x8 af[4], bfr[4]; \
    _Pragma("unroll") for (int mi=0;mi<4;mi++) \
      af[mi] = *(const bf16x8*)((A_) + (size_t)(mbase+mi*16+lr)*(lda_) + k + kg); \
    _Pragma("unroll") for (int ni=0;ni<4;ni++) \
      bfr[ni] = *(const bf16x8*)((B_) + (size_t)(nbase+ni*16+lr)*(ldb_) + k + kg); \
    _Pragma("unroll") for (int mi=0;mi<4;mi++) \
      _Pragma("unroll") for (int ni=0;ni<4;ni++) \
        acc[mi][ni] = __builtin_amdgcn_mfma_f32_16x16x32_bf16(af[mi], bfr[ni], acc[mi][ni], 0, 0, 0); \
  }

// ---------------- xp = pred[:,0:256]@WiB.T + tables + bi ----------------
__global__ __launch_bounds__(256) void gemm_xp(const bf16* __restrict__ pred,
        const bf16* __restrict__ WiB, const float* __restrict__ bi,
        const float* __restrict__ Tans, const float* __restrict__ Tcae,
        const float* __restrict__ Tlab,
        const float* __restrict__ tm, const float* __restrict__ vm,
        const float* __restrict__ lm,
        const int* __restrict__ ans, const int* __restrict__ cans,
        const float* __restrict__ labels, float* __restrict__ xp){
  MFMA_CORE(pred, PP, WiB, 256, 256)
  #pragma unroll
  for (int mi=0;mi<4;mi++){
    #pragma unroll
    for (int r=0;r<4;r++){
      int row = mbase + mi*16 + (lane>>4)*4 + r;
      float mk = tm[row]*vm[row]*lm[row];
      int a = ans[row], ca = cans[row], lb = (int)labels[row];
      #pragma unroll
      for (int ni=0;ni<4;ni++){
        int c = nbase + ni*16 + lr;
        xp[(size_t)row*G3 + c] = acc[mi][ni][r] + bi[c]
            + mk*Tans[a*G3+c] + Tcae[ca*G3+c] + mk*Tlab[lb*G3+c];
      }
    }
  }
}

// ---------------- h1 = relu(pred@l1W.T + b) (bf16 out) ----------------
__global__ __launch_bounds__(256) void gemm_l1(const bf16* __restrict__ pred,
        const bf16* __restrict__ Wb, const float* __restrict__ bias,
        bf16* __restrict__ h1){
  MFMA_CORE(pred, PP, Wb, PP, PP)
  #pragma unroll
  for (int mi=0;mi<4;mi++){
    #pragma unroll
    for (int ni=0;ni<4;ni++){
      int c = nbase + ni*16 + lr;
      float bia = bias[c];
      #pragma unroll
      for (int r=0;r<4;r++){
        int row = mbase + mi*16 + (lane>>4)*4 + r;
        h1[(size_t)row*PP + c] = __float2bfloat16(fmaxf(acc[mi][ni][r] + bia, 0.f));
      }
    }
  }
}

// ---------------- h2 tile + fused (h2+pred)@outW partial into logits ----------------
__global__ __launch_bounds__(256) void gemm_l2_logits(const bf16* __restrict__ h1,
        const bf16* __restrict__ Wb, const float* __restrict__ bias,
        const bf16* __restrict__ pred, const float* __restrict__ outW,
        float* __restrict__ logits){
  MFMA_CORE(h1, PP, Wb, PP, PP)
  #pragma unroll
  for (int mi=0;mi<4;mi++){
    #pragma unroll
    for (int r=0;r<4;r++){
      int row = mbase + mi*16 + (lane>>4)*4 + r;
      float p = 0.f;
      #pragma unroll
      for (int ni=0;ni<4;ni++){
        int c = nbase + ni*16 + lr;
        float h2v = fmaxf(acc[mi][ni][r] + bias[c], 0.f);
        p += (h2v + __bfloat162float(pred[(size_t)row*PP + c])) * outW[c];
      }
      p += __shfl_xor(p,1);
      p += __shfl_xor(p,2);
      p += __shfl_xor(p,4);
      p += __shfl_xor(p,8);
      if (lr == 0) atomicAdd(&logits[row], p);
    }
  }
}

// ================= MFMA GRU scan (double-buffered, no vmcnt drain) =================
// 16 blocks x 16 batch rows, 8 waves. Wh fragments permanently in VGPRs.
// h transits a double-buffered XOR-swizzled LDS tile (4KB each). One raw
// s_barrier per step with lgkmcnt(0) only -> xp prefetch loads and pred
// stores stay in flight across barriers (T4: never drain vmcnt in loop).
__global__ __launch_bounds__(512, 1) void gru_scan_mfma(const float* __restrict__ xp,
        const float* __restrict__ Wh, const float* __restrict__ bh,
        bf16* __restrict__ pred){
  __shared__ __align__(16) char hbf[8192];   // 2 x bf16 h[16][128], swizzled
  const int tid  = threadIdx.x;
  const int lane = tid & 63;
  const int w    = tid >> 6;        // wave 0..7
  const int lr   = lane & 15;       // A-row (batch) / d-within-wave
  const int lg   = lane >> 4;       // 0..3: k-group / batch-group
  const int d    = w*16 + lr;       // h-dim this lane owns for gates
  const int bg0  = blockIdx.x * 16; // global batch base

  // ---- preload Wh fragments (bf16) ----
  union U8 { bf16x8 v; unsigned short s[8]; };
  bf16x8 wf0[4], wf1[4], wf2[4];
  #pragma unroll
  for (int kk=0; kk<4; kk++){
    #pragma unroll
    for (int g=0; g<3; g++){
      const float* src = Wh + (size_t)(g*HH + d)*HH + kk*32 + lg*8;
      U8 u;
      #pragma unroll
      for (int j=0;j<8;j++){
        bf16 bv = __float2bfloat16(src[j]);
        u.s[j] = reinterpret_cast<unsigned short&>(bv);
      }
      if (g==0) wf0[kk]=u.v; else if (g==1) wf1[kk]=u.v; else wf2[kk]=u.v;
    }
  }
  const float bh0 = bh[d], bh1 = bh[HH+d], bh2 = bh[2*HH+d];

  float h[4] = {0.f,0.f,0.f,0.f};
  ((unsigned long long*)hbf)[tid]       = 0ULL;   // zero both 4KB buffers
  ((unsigned long long*)hbf)[tid + 512] = 0ULL;

  float xA[12], xB[12];
#define LOADX(X_, t_) do{ if ((t_) < SS){ \
    _Pragma("unroll") for (int q=0;q<4;q++){ \
      const float* xr_ = xp + ((size_t)(t_)*BB + bg0 + lg*4 + q)*G3 + d; \
      X_[q*3+0] = xr_[0]; X_[q*3+1] = xr_[HH]; X_[q*3+2] = xr_[2*HH]; \
    } } }while(0)

  LOADX(xA, 0);
  LOADX(xB, 1);
  __syncthreads();

#define GSTEP(t_, X_, RO_, WO_) { \
    f32x4 ac0 = (f32x4){0.f,0.f,0.f,0.f}, ac1 = ac0, ac2 = ac0; \
    _Pragma("unroll") for (int kk=0; kk<4; kk++){ \
      bf16x8 a = *(const bf16x8*)(hbf + (RO_) + lr*256 + ((kk*64 + lg*16) ^ ((lr&7)<<4))); \
      ac0 = __builtin_amdgcn_mfma_f32_16x16x32_bf16(a, wf0[kk], ac0, 0,0,0); \
      ac1 = __builtin_amdgcn_mfma_f32_16x16x32_bf16(a, wf1[kk], ac1, 0,0,0); \
      ac2 = __builtin_amdgcn_mfma_f32_16x16x32_bf16(a, wf2[kk], ac2, 0,0,0); \
    } \
    float hold[4]; \
    _Pragma("unroll") for (int q=0;q<4;q++){ \
      float r  = sigf2(X_[q*3+0] + ac0[q] + bh0); \
      float zg = sigf2(X_[q*3+1] + ac1[q] + bh1); \
      float n  = tanhf2(X_[q*3+2] + r*(ac2[q] + bh2)); \
      hold[q] = h[q]; \
      h[q] = (1.f - zg)*n + zg*h[q]; \
    } \
    _Pragma("unroll") for (int q=0;q<4;q++) \
      pred[((size_t)(t_)*BB + bg0 + lg*4 + q)*PP + 256 + d] = __float2bfloat16(hold[q]); \
    LOADX(X_, (t_)+2); \
    _Pragma("unroll") for (int q=0;q<4;q++){ \
      int B_ = lg*4 + q; \
      *(bf16*)(hbf + (WO_) + B_*256 + ((2*d) ^ ((B_&7)<<4))) = __float2bfloat16(h[q]); \
    } \
    asm volatile("s_waitcnt lgkmcnt(0)" ::: "memory"); \
    __builtin_amdgcn_s_barrier(); \
    __builtin_amdgcn_sched_barrier(0); \
  }

  for (int t=0; t<SS; t+=2){
    GSTEP(t,   xA, 0,    4096)
    GSTEP(t+1, xB, 4096, 0)
  }
#undef GSTEP
#undef LOADX
}

// ---------------- loss + probs ----------------
__global__ __launch_bounds__(256) void loss_probs_k(const float* __restrict__ logits,
        const float* __restrict__ labels, const float* __restrict__ tm,
        const float* __restrict__ vm, const float* __restrict__ lm,
        const float* __restrict__ out_b, float* __restrict__ out,
        float* __restrict__ lacc){
  int i = blockIdx.x*256 + threadIdx.x;
  float x = logits[i] + out_b[0];
  float lb = labels[i];
  float mk = tm[i]*vm[i]*lm[i];
  float sp = fmaxf(x,0.f) + log1pf(expf(-fabsf(x)));
  float pe = (sp - x*lb)*mk;
  out[1+i] = sigf(x);
  float v0 = pe, v1 = mk;
  for (int o=32;o>0;o>>=1){ v0 += __shfl_down(v0,o); v1 += __shfl_down(v1,o); }
  if ((threadIdx.x & 63)==0){ atomicAdd(&lacc[0], v0); atomicAdd(&lacc[1], v1); }
}

__global__ void finalize_k(const float* __restrict__ lacc, float* __restrict__ out){
  out[0] = lacc[0]/lacc[1];
}

// ---------------- launch ----------------
extern "C" void kernel_launch(void* const* d_in, const int* in_sizes, int n_in,
                              void* d_out, int out_size, void* d_ws, size_t ws_size,
                              hipStream_t stream) {
  const float* q_emb   = (const float*)d_in[0];
  const float* s_emb   = (const float*)d_in[1];
  const float* ans_emb = (const float*)d_in[2];
  const float* lab_emb = (const float*)d_in[3];
  const float* gru_Wi  = (const float*)d_in[4];
  const float* gru_Wh  = (const float*)d_in[5];
  const float* gru_bi  = (const float*)d_in[6];
  const float* gru_bh  = (const float*)d_in[7];
  const float* s2s_W   = (const float*)d_in[8];
  const float* s2s_b   = (const float*)d_in[9];
  const float* s2q_W   = (const float*)d_in[10];
  const float* s2q_b   = (const float*)d_in[11];
  const float* q2q_W   = (const float*)d_in[12];
  const float* q2q_b   = (const float*)d_in[13];
  const float* q2s_W   = (const float*)d_in[14];
  const float* q2s_b   = (const float*)d_in[15];
  const float* l1_W    = (const float*)d_in[16];
  const float* l1_b    = (const float*)d_in[17];
  const float* l2_W    = (const float*)d_in[18];
  const float* l2_b    = (const float*)d_in[19];
  const float* out_W   = (const float*)d_in[20];
  const float* out_b   = (const float*)d_in[21];
  const float* tm      = (const float*)d_in[22];
  const float* vm      = (const float*)d_in[23];
  const float* lm      = (const float*)d_in[24];
  const float* smask   = (const float*)d_in[25];
  const float* q_mask  = (const float*)d_in[26];
  const float* labels  = (const float*)d_in[27];
  const int*   ans     = (const int*)d_in[28];
  const int*   cans    = (const int*)d_in[29];
  const int*   sub_ids = (const int*)d_in[30];
  const int*   q_ids   = (const int*)d_in[31];
  const int*   q_map   = (const int*)d_in[32];

  // ---- workspace layout (byte offsets, 256B-aligned) ----
  char* wsb = (char*)d_ws;
  size_t off = 0;
  auto alloc = [&](size_t bytes) -> char* {
    char* p = wsb + off;
    off += (bytes + 255) & ~(size_t)255;
    return p;
  };
  float* sums   = (float*)alloc((size_t)REPL*51200*4);   // [R][Ns,D]
  float* cnts   = (float*)alloc((size_t)REPL*400*4);     // [R][Ns]
  float* subj1  = (float*)alloc(51200*4);
  float* Tans   = (float*)alloc(4*G3*4);
  float* Tcae   = (float*)alloc(4*G3*4);
  float* Tlab   = (float*)alloc(2*G3*4);
  float* lacc   = (float*)alloc(2*4);
  float* logits = (float*)alloc((size_t)SB*4);
  bf16*  l1Wb   = (bf16*) alloc((size_t)512*512*2);
  bf16*  l2Wb   = (bf16*) alloc((size_t)512*512*2);
  bf16*  WiB    = (bf16*) alloc((size_t)384*256*2);
  bf16*  q1     = (bf16*) alloc((size_t)NQ*DD*2);        // 7.68 MB
  bf16*  pred   = (bf16*) alloc((size_t)SB*PP*2);        // 52.4 MB
  char*  xh     = alloc((size_t)SB*G3*4);                // 78.6 MB: xp f32, then h1 bf16
  float* xp     = (float*)xh;
  bf16*  h1     = (bf16*)xh;   // aliased: xp dead after gru_scan
  float* out    = (float*)d_out;

  hipMemsetAsync(sums, 0, (size_t)REPL*(51200+400)*sizeof(float), stream);
  hipMemsetAsync(lacc, 0, 2*sizeof(float), stream);
  hipMemsetAsync(logits, 0, (size_t)SB*sizeof(float), stream);

  tables_k<<<dim3(3), dim3(128), 0, stream>>>(ans_emb, lab_emb, gru_Wi, Tans, Tcae, Tlab);
  conv_w_k<<<dim3(1024), dim3(256), 0, stream>>>(l1_W, l2_W, gru_Wi, l1Wb, l2Wb, WiB);
  q2s_scatter<<<dim3(NQ/QPB), dim3(128), 0, stream>>>(q_emb, q2s_W, q2s_b, q_map, sums, cnts);
  subjects1_k<<<dim3(NS), dim3(128), 0, stream>>>(s_emb, s2s_W, s2s_b, sums, cnts, subj1);
  questions1_k<<<dim3(NQ/QPB), dim3(128), 0, stream>>>(q_emb, subj1, q_map, q_mask,
                                                       s2q_W, s2q_b, q2q_W, q2q_b, q1);
  assemble_k<<<dim3(SB), dim3(128), 0, stream>>>(q1, subj1, ans_emb, cans, sub_ids, smask, q_ids, pred);
  // grid: x = m-blocks (fast-varying -> W panel stays L2-hot), y = n-blocks
  gemm_xp<<<dim3(400,3), dim3(256), 0, stream>>>(pred, WiB, gru_bi, Tans, Tcae, Tlab,
                                                 tm, vm, lm, ans, cans, labels, xp);
  gru_scan_mfma<<<dim3(16), dim3(512), 0, stream>>>(xp, gru_Wh, gru_bh, pred);
  gemm_l1<<<dim3(400,4), dim3(256), 0, stream>>>(pred, l1Wb, l1_b, h1);
  gemm_l2_logits<<<dim3(400,4), dim3(256), 0, stream>>>(h1, l2Wb, l2_b, pred, out_W, logits);
  loss_probs_k<<<dim3(SB/256), dim3(256), 0, stream>>>(logits, labels, tm, vm, lm, out_b, out, lacc);
  finalize_k<<<dim3(1), dim3(1), 0, stream>>>(lacc, out);
}

// Round 8
// 933.684 us; speedup vs baseline: 1.1030x; 1.0487x over previous
//
#include <hip/hip_runtime.h>
#include <hip/hip_bf16.h>
#include <math.h>

#define NQ 30000
#define NS 400
#define DD 128
#define HH 128
#define SS 200
#define BB 256
#define MSq 4
#define MBs 4
#define PP 512
#define SB (SS*BB)      // 51200
#define G3 384          // 3*H
#define QPB 16
#define REPL 8          // q2s atomic replicas
#define TST (48*2048)   // xp2 halfs per timestep (16 blk * 3 gates * 128 d * 16 b)

typedef __hip_bfloat16 bf16;
typedef __attribute__((ext_vector_type(8))) short bf16x8;
typedef __attribute__((ext_vector_type(4))) float f32x4;
typedef __attribute__((ext_vector_type(4))) _Float16 f16x4;

__device__ __forceinline__ float sigf(float x){ return 1.0f/(1.0f+expf(-x)); }
__device__ __forceinline__ float sigf2(float x){ return 1.0f/(1.0f+__expf(-x)); }
__device__ __forceinline__ float tanhf2(float x){ return 1.0f - 2.0f/(__expf(2.0f*x)+1.0f); }

// ---------------- tables: T_ans = ans_emb @ Wi[:,0:128].T etc ----------------
__global__ __launch_bounds__(128) void tables_k(const float* __restrict__ ans_emb,
        const float* __restrict__ label_emb, const float* __restrict__ Wi,
        float* __restrict__ Tans, float* __restrict__ Tcae, float* __restrict__ Tlab){
  int j = blockIdx.x*128 + threadIdx.x;
  if (j >= G3) return;
  const float* wr = Wi + (size_t)j*640;
  for (int a=0;a<4;a++){
    float acc=0.f;
    for (int k=0;k<DD;k++) acc += ans_emb[a*DD+k]*wr[k];
    Tans[a*G3+j]=acc;
  }
  for (int a=0;a<4;a++){
    float acc=0.f;
    for (int k=0;k<DD;k++) acc += ans_emb[a*DD+k]*wr[128+k];
    Tcae[a*G3+j]=acc;
  }
  for (int l=0;l<2;l++){
    float acc=0.f;
    for (int k=0;k<DD;k++) acc += label_emb[l*DD+k]*wr[256+k];
    Tlab[l*G3+j]=acc;
  }
}

// ---------------- weight convert: f32 -> bf16 ----------------
__global__ __launch_bounds__(256) void conv_w_k(const float* __restrict__ l1W,
        const float* __restrict__ l2W, const float* __restrict__ Wi,
        bf16* __restrict__ l1Wb, bf16* __restrict__ l2Wb, bf16* __restrict__ WiB){
  int i = blockIdx.x*256 + threadIdx.x;
  if (i < 512*512){
    l1Wb[i] = __float2bfloat16(l1W[i]);
    l2Wb[i] = __float2bfloat16(l2W[i]);
  }
  if (i < 384*256){
    int j = i >> 8, k = i & 255;
    WiB[i] = __float2bfloat16(Wi[j*640 + 384 + k]);
  }
}

// ---------------- q2s projection + scatter (8-way replicated atomics) ----------------
__global__ __launch_bounds__(128) void q2s_scatter(const float* __restrict__ q_emb,
        const float* __restrict__ W, const float* __restrict__ bias,
        const int* __restrict__ q_map, float* __restrict__ sums, float* __restrict__ cnts){
  __shared__ float qe[QPB][DD];
  int q0 = blockIdx.x*QPB;
  int tid = threadIdx.x;
  float* S = sums + (size_t)(blockIdx.x & (REPL-1))*51200;
  float* C = cnts + (size_t)(blockIdx.x & (REPL-1))*400;
  for (int r=0;r<QPB;r++) qe[r][tid] = q_emb[(size_t)(q0+r)*DD + tid];
  __syncthreads();
  float acc[QPB];
  #pragma unroll
  for (int r=0;r<QPB;r++) acc[r] = bias[tid];
  const float4* wr = (const float4*)(W + (size_t)tid*DD);
  #pragma unroll 4
  for (int k4=0;k4<DD/4;k4++){
    float4 w = wr[k4];
    #pragma unroll
    for (int r=0;r<QPB;r++){
      acc[r] += w.x*qe[r][k4*4] + w.y*qe[r][k4*4+1] + w.z*qe[r][k4*4+2] + w.w*qe[r][k4*4+3];
    }
  }
  for (int r=0;r<QPB;r++){
    int q = q0+r;
    #pragma unroll
    for (int m=0;m<MSq;m++){
      int s = q_map[q*MSq+m];
      atomicAdd(&S[(size_t)s*DD + tid], acc[r]);
      if (tid==0) atomicAdd(&C[s], 1.0f);
    }
  }
}

// ---------------- subjects_1 (reduces the replicas) ----------------
__global__ __launch_bounds__(128) void subjects1_k(const float* __restrict__ s_emb,
        const float* __restrict__ W, const float* __restrict__ bias,
        const float* __restrict__ sums, const float* __restrict__ cnts,
        float* __restrict__ out){
  __shared__ float se[DD];
  int s = blockIdx.x; int tid = threadIdx.x;
  se[tid] = s_emb[(size_t)s*DD+tid];
  __syncthreads();
  float acc = bias[tid];
  const float4* wr = (const float4*)(W + (size_t)tid*DD);
  for (int k4=0;k4<DD/4;k4++){
    float4 w = wr[k4];
    acc += w.x*se[k4*4] + w.y*se[k4*4+1] + w.z*se[k4*4+2] + w.w*se[k4*4+3];
  }
  float c = 0.f, sm = 0.f;
  #pragma unroll
  for (int r=0;r<REPL;r++){
    c  += cnts[r*400 + s];
    sm += sums[(size_t)r*51200 + (size_t)s*DD + tid];
  }
  float v = 0.f;
  if (c > 0.f) v = tanhf(sm/fmaxf(c,1.f) + acc);
  out[(size_t)s*DD+tid] = v;
}

// ---------------- questions_1 (bf16 out) ----------------
__global__ __launch_bounds__(128) void questions1_k(const float* __restrict__ q_emb,
        const float* __restrict__ subj1, const int* __restrict__ q_map,
        const float* __restrict__ q_mask,
        const float* __restrict__ s2qW, const float* __restrict__ s2qb,
        const float* __restrict__ q2qW, const float* __restrict__ q2qb,
        bf16* __restrict__ q1out){
  __shared__ float qe[QPB][DD];
  __shared__ float nq[QPB][DD];
  int q0 = blockIdx.x*QPB; int tid = threadIdx.x;
  for (int r=0;r<QPB;r++){
    int q = q0+r;
    qe[r][tid] = q_emb[(size_t)q*DD+tid];
    float sum=0.f, wsum=0.f;
    #pragma unroll
    for (int m=0;m<MSq;m++){
      float w = q_mask[q*MSq+m];
      sum += subj1[(size_t)q_map[q*MSq+m]*DD + tid]*w;
      wsum += w;
    }
    nq[r][tid] = sum / wsum;
  }
  __syncthreads();
  float acc[QPB];
  #pragma unroll
  for (int r=0;r<QPB;r++) acc[r] = s2qb[tid]+q2qb[tid];
  const float4* w1 = (const float4*)(s2qW + (size_t)tid*DD);
  const float4* w2 = (const float4*)(q2qW + (size_t)tid*DD);
  #pragma unroll 2
  for (int k4=0;k4<DD/4;k4++){
    float4 a = w1[k4]; float4 b = w2[k4];
    #pragma unroll
    for (int r=0;r<QPB;r++){
      acc[r] += a.x*nq[r][k4*4] + a.y*nq[r][k4*4+1] + a.z*nq[r][k4*4+2] + a.w*nq[r][k4*4+3]
              + b.x*qe[r][k4*4] + b.y*qe[r][k4*4+1] + b.z*qe[r][k4*4+2] + b.w*qe[r][k4*4+3];
    }
  }
  for (int r=0;r<QPB;r++) q1out[(size_t)(q0+r)*DD+tid] = __float2bfloat16(tanhf(acc[r]));
}

// ---------------- assemble pred_input cols 0:256 and 384:512 (bf16) ----------------
__global__ __launch_bounds__(128) void assemble_k(const bf16* __restrict__ q1,
        const float* __restrict__ subj1, const float* __restrict__ ans_emb,
        const int* __restrict__ cans, const int* __restrict__ sub_ids,
        const float* __restrict__ sub_mask, const int* __restrict__ q_ids,
        bf16* __restrict__ pred){
  int i = blockIdx.x; int d = threadIdx.x;
  size_t base = (size_t)i*PP;
  pred[base + d] = q1[(size_t)q_ids[i]*DD + d];
  float s = 0.f;
  #pragma unroll
  for (int m=0;m<MBs;m++)
    s += subj1[(size_t)sub_ids[i*MBs+m]*DD+d]*sub_mask[i*MBs+m];
  pred[base+128+d] = __float2bfloat16(s);
  pred[base+384+d] = __float2bfloat16(ans_emb[(size_t)cans[i]*DD + d]);
}

// ======== MFMA GEMM core (unchanged, verified) ========
#define MFMA_CORE(A_, lda_, B_, ldb_, K_) \
  int lane = threadIdx.x & 63; int wid = threadIdx.x >> 6; \
  int wy = wid >> 1, wx = wid & 1; \
  int mbase = blockIdx.x*128 + wy*64; \
  int nbase = blockIdx.y*128 + wx*64; \
  int lr = lane & 15, kg = (lane >> 4) * 8; \
  f32x4 acc[4][4]; \
  _Pragma("unroll") for (int i=0;i<4;i++) _Pragma("unroll") for (int j=0;j<4;j++) acc[i][j] = (f32x4){0.f,0.f,0.f,0.f}; \
  for (int k=0; k<(K_); k+=32){ \
    bf16x8 af[4], bfr[4]; \
    _Pragma("unroll") for (int mi=0;mi<4;mi++) \
      af[mi] = *(const bf16x8*)((A_) + (size_t)(mbase+mi*16+lr)*(lda_) + k + kg); \
    _Pragma("unroll") for (int ni=0;ni<4;ni++) \
      bfr[ni] = *(const bf16x8*)((B_) + (size_t)(nbase+ni*16+lr)*(ldb_) + k + kg); \
    _Pragma("unroll") for (int mi=0;mi<4;mi++) \
      _Pragma("unroll") for (int ni=0;ni<4;ni++) \
        acc[mi][ni] = __builtin_amdgcn_mfma_f32_16x16x32_bf16(af[mi], bfr[ni], acc[mi][ni], 0, 0, 0); \
  }

// ---------------- xp2 (fp16, GRU-block-transposed) = pred[:,0:256]@WiB.T + tables + bi (+bh r,z) ----------------
// layout: xp2[((t*16 + b>>4)*3 + g)*2048 + d*16 + (b&15)]
__global__ __launch_bounds__(256) void gemm_xp(const bf16* __restrict__ pred,
        const bf16* __restrict__ WiB, const float* __restrict__ bi,
        const float* __restrict__ bh,
        const float* __restrict__ Tans, const float* __restrict__ Tcae,
        const float* __restrict__ Tlab,
        const float* __restrict__ tm, const float* __restrict__ vm,
        const float* __restrict__ lm,
        const int* __restrict__ ans, const int* __restrict__ cans,
        const float* __restrict__ labels, _Float16* __restrict__ xp2){
  MFMA_CORE(pred, PP, WiB, 256, 256)
  #pragma unroll
  for (int mi=0;mi<4;mi++){
    #pragma unroll
    for (int r=0;r<4;r++){
      int row = mbase + mi*16 + (lane>>4)*4 + r;
      int t = row >> 8, b = row & 255;
      size_t rowpart = ((size_t)t*48 + (b>>4)*3)*2048 + (b&15);
      float mk = tm[row]*vm[row]*lm[row];
      int a = ans[row], ca = cans[row], lb = (int)labels[row];
      #pragma unroll
      for (int ni=0;ni<4;ni++){
        int c = nbase + ni*16 + lr;
        int g = c >> 7, dd = c & 127;
        float v = acc[mi][ni][r] + bi[c]
            + mk*Tans[a*G3+c] + Tcae[ca*G3+c] + mk*Tlab[lb*G3+c];
        if (g < 2) v += bh[c];            // fold r,z hidden bias (n bias stays in GRU)
        xp2[rowpart + (size_t)(g*2048 + dd*16)] = (_Float16)v;
      }
    }
  }
}

// ---------------- h1 = relu(pred@l1W.T + b) (bf16 out) ----------------
__global__ __launch_bounds__(256) void gemm_l1(const bf16* __restrict__ pred,
        const bf16* __restrict__ Wb, const float* __restrict__ bias,
        bf16* __restrict__ h1){
  MFMA_CORE(pred, PP, Wb, PP, PP)
  #pragma unroll
  for (int mi=0;mi<4;mi++){
    #pragma unroll
    for (int ni=0;ni<4;ni++){
      int c = nbase + ni*16 + lr;
      float bia = bias[c];
      #pragma unroll
      for (int r=0;r<4;r++){
        int row = mbase + mi*16 + (lane>>4)*4 + r;
        h1[(size_t)row*PP + c] = __float2bfloat16(fmaxf(acc[mi][ni][r] + bia, 0.f));
      }
    }
  }
}

// ---------------- h2 tile + fused (h2+pred)@outW partial into logits ----------------
__global__ __launch_bounds__(256) void gemm_l2_logits(const bf16* __restrict__ h1,
        const bf16* __restrict__ Wb, const float* __restrict__ bias,
        const bf16* __restrict__ pred, const float* __restrict__ outW,
        float* __restrict__ logits){
  MFMA_CORE(h1, PP, Wb, PP, PP)
  #pragma unroll
  for (int mi=0;mi<4;mi++){
    #pragma unroll
    for (int r=0;r<4;r++){
      int row = mbase + mi*16 + (lane>>4)*4 + r;
      float p = 0.f;
      #pragma unroll
      for (int ni=0;ni<4;ni++){
        int c = nbase + ni*16 + lr;
        float h2v = fmaxf(acc[mi][ni][r] + bias[c], 0.f);
        p += (h2v + __bfloat162float(pred[(size_t)row*PP + c])) * outW[c];
      }
      p += __shfl_xor(p,1);
      p += __shfl_xor(p,2);
      p += __shfl_xor(p,4);
      p += __shfl_xor(p,8);
      if (lr == 0) atomicAdd(&logits[row], p);
    }
  }
}

// ================= MFMA GRU scan (fp16 x, coalesced, LDS-flush pred) =================
__global__ __launch_bounds__(512, 1) void gru_scan_mfma(const _Float16* __restrict__ xp2,
        const float* __restrict__ Wh, const float* __restrict__ bh,
        bf16* __restrict__ pred){
  __shared__ __align__(16) char hbf[8192];   // 2 x bf16 h[16 b][128 d], XOR-swizzled
  const int tid  = threadIdx.x;
  const int lane = tid & 63;
  const int w    = tid >> 6;        // wave 0..7
  const int lr   = lane & 15;
  const int lg   = lane >> 4;       // 0..3
  const int d    = w*16 + lr;       // owned h-dim
  const int bg0  = blockIdx.x * 16;

  // ---- Wh fragments (bf16, permanent) ----
  union U8 { bf16x8 v; unsigned short s[8]; };
  bf16x8 wf0[4], wf1[4], wf2[4];
  #pragma unroll
  for (int kk=0; kk<4; kk++){
    #pragma unroll
    for (int g=0; g<3; g++){
      const float* src = Wh + (size_t)(g*HH + d)*HH + kk*32 + lg*8;
      U8 u;
      #pragma unroll
      for (int j=0;j<8;j++){
        bf16 bv = __float2bfloat16(src[j]);
        u.s[j] = reinterpret_cast<unsigned short&>(bv);
      }
      if (g==0) wf0[kk]=u.v; else if (g==1) wf1[kk]=u.v; else wf2[kk]=u.v;
    }
  }
  const float bh2 = bh[2*HH+d];

  // ---- precomputed LDS addresses (zero per-step addressing VALU) ----
  int rdaddr[4];
  #pragma unroll
  for (int kk=0;kk<4;kk++) rdaddr[kk] = lr*256 + ((kk*64 + lg*16) ^ ((lr&7)<<4));
  int wraddr[4];
  #pragma unroll
  for (int q=0;q<4;q++){
    int B_ = lg*4 + q;
    wraddr[q] = B_*256 + ((2*d) ^ ((B_&7)<<4));
  }
  // flush mapping (threads 0..255): row fB, 16B-block fblk
  const int fB = tid >> 4, fblk = tid & 15;
  const int faddr = fB*256 + ((fblk*16) ^ ((fB&7)<<4));
  bf16* fptr = pred + ((size_t)bg0 + fB)*PP + 256 + fblk*8;
  const size_t PSTRIDE = (size_t)BB*PP;

  float h0=0.f, h1v=0.f, h2v=0.f, h3v=0.f;
  ((unsigned long long*)hbf)[tid]       = 0ULL;
  ((unsigned long long*)hbf)[tid + 512] = 0ULL;

  // ---- x: 3 coalesced 8B loads/step, 2-step prefetch ----
  const _Float16* x0 = xp2 + (size_t)blockIdx.x*3*2048 + d*16 + lg*4;
  f16x4 xrA = *(const f16x4*)(x0);
  f16x4 xzA = *(const f16x4*)(x0 + 2048);
  f16x4 xnA = *(const f16x4*)(x0 + 4096);
  f16x4 xrB = *(const f16x4*)(x0 + TST);
  f16x4 xzB = *(const f16x4*)(x0 + TST + 2048);
  f16x4 xnB = *(const f16x4*)(x0 + TST + 4096);
  const _Float16* xtr = x0 + 2*(size_t)TST;
  const _Float16* xtz = xtr + 2048;
  const _Float16* xtn = xtr + 4096;

  __syncthreads();

#define GATEQ(Q, CR, CZ, CN, HV) { \
    float r  = sigf2((float)(CR) + ac0[Q]); \
    float zg = sigf2((float)(CZ) + ac1[Q]); \
    float n  = tanhf2((float)(CN) + r*(ac2[Q] + bh2)); \
    HV = (1.f - zg)*n + zg*HV; }

#define GSTEP(RO_, WO_, XR, XZ, XN) { \
    f32x4 ac0 = (f32x4){0.f,0.f,0.f,0.f}, ac1 = ac0, ac2 = ac0; \
    _Pragma("unroll") for (int kk=0; kk<4; kk++){ \
      bf16x8 a = *(const bf16x8*)(hbf + (RO_) + rdaddr[kk]); \
      ac0 = __builtin_amdgcn_mfma_f32_16x16x32_bf16(a, wf0[kk], ac0, 0,0,0); \
      ac1 = __builtin_amdgcn_mfma_f32_16x16x32_bf16(a, wf1[kk], ac1, 0,0,0); \
      ac2 = __builtin_amdgcn_mfma_f32_16x16x32_bf16(a, wf2[kk], ac2, 0,0,0); \
    } \
    if (tid < 256){  /* flush forward_ht = h(t) from RO buffer, coalesced */ \
      int4 hv = *(const int4*)(hbf + (RO_) + faddr); \
      *(int4*)fptr = hv; \
    } \
    fptr += PSTRIDE; \
    GATEQ(0, (XR).x, (XZ).x, (XN).x, h0) \
    GATEQ(1, (XR).y, (XZ).y, (XN).y, h1v) \
    GATEQ(2, (XR).z, (XZ).z, (XN).z, h2v) \
    GATEQ(3, (XR).w, (XZ).w, (XN).w, h3v) \
    *(bf16*)(hbf + (WO_) + wraddr[0]) = __float2bfloat16(h0); \
    *(bf16*)(hbf + (WO_) + wraddr[1]) = __float2bfloat16(h1v); \
    *(bf16*)(hbf + (WO_) + wraddr[2]) = __float2bfloat16(h2v); \
    *(bf16*)(hbf + (WO_) + wraddr[3]) = __float2bfloat16(h3v); \
    XR = *(const f16x4*)(xtr); XZ = *(const f16x4*)(xtz); XN = *(const f16x4*)(xtn); \
    xtr += TST; xtz += TST; xtn += TST; \
    asm volatile("s_waitcnt lgkmcnt(0)" ::: "memory"); \
    __builtin_amdgcn_s_barrier(); \
    __builtin_amdgcn_sched_barrier(0); \
  }

  for (int t=0; t<SS; t+=2){
    GSTEP(0,    4096, xrA, xzA, xnA)
    GSTEP(4096, 0,    xrB, xzB, xnB)
  }
#undef GSTEP
#undef GATEQ
}

// ---------------- loss + probs ----------------
__global__ __launch_bounds__(256) void loss_probs_k(const float* __restrict__ logits,
        const float* __restrict__ labels, const float* __restrict__ tm,
        const float* __restrict__ vm, const float* __restrict__ lm,
        const float* __restrict__ out_b, float* __restrict__ out,
        float* __restrict__ lacc){
  int i = blockIdx.x*256 + threadIdx.x;
  float x = logits[i] + out_b[0];
  float lb = labels[i];
  float mk = tm[i]*vm[i]*lm[i];
  float sp = fmaxf(x,0.f) + log1pf(expf(-fabsf(x)));
  float pe = (sp - x*lb)*mk;
  out[1+i] = sigf(x);
  float v0 = pe, v1 = mk;
  for (int o=32;o>0;o>>=1){ v0 += __shfl_down(v0,o); v1 += __shfl_down(v1,o); }
  if ((threadIdx.x & 63)==0){ atomicAdd(&lacc[0], v0); atomicAdd(&lacc[1], v1); }
}

__global__ void finalize_k(const float* __restrict__ lacc, float* __restrict__ out){
  out[0] = lacc[0]/lacc[1];
}

// ---------------- launch ----------------
extern "C" void kernel_launch(void* const* d_in, const int* in_sizes, int n_in,
                              void* d_out, int out_size, void* d_ws, size_t ws_size,
                              hipStream_t stream) {
  const float* q_emb   = (const float*)d_in[0];
  const float* s_emb   = (const float*)d_in[1];
  const float* ans_emb = (const float*)d_in[2];
  const float* lab_emb = (const float*)d_in[3];
  const float* gru_Wi  = (const float*)d_in[4];
  const float* gru_Wh  = (const float*)d_in[5];
  const float* gru_bi  = (const float*)d_in[6];
  const float* gru_bh  = (const float*)d_in[7];
  const float* s2s_W   = (const float*)d_in[8];
  const float* s2s_b   = (const float*)d_in[9];
  const float* s2q_W   = (const float*)d_in[10];
  const float* s2q_b   = (const float*)d_in[11];
  const float* q2q_W   = (const float*)d_in[12];
  const float* q2q_b   = (const float*)d_in[13];
  const float* q2s_W   = (const float*)d_in[14];
  const float* q2s_b   = (const float*)d_in[15];
  const float* l1_W    = (const float*)d_in[16];
  const float* l1_b    = (const float*)d_in[17];
  const float* l2_W    = (const float*)d_in[18];
  const float* l2_b    = (const float*)d_in[19];
  const float* out_W   = (const float*)d_in[20];
  const float* out_b   = (const float*)d_in[21];
  const float* tm      = (const float*)d_in[22];
  const float* vm      = (const float*)d_in[23];
  const float* lm      = (const float*)d_in[24];
  const float* smask   = (const float*)d_in[25];
  const float* q_mask  = (const float*)d_in[26];
  const float* labels  = (const float*)d_in[27];
  const int*   ans     = (const int*)d_in[28];
  const int*   cans    = (const int*)d_in[29];
  const int*   sub_ids = (const int*)d_in[30];
  const int*   q_ids   = (const int*)d_in[31];
  const int*   q_map   = (const int*)d_in[32];

  // ---- workspace layout ----
  char* wsb = (char*)d_ws;
  size_t off = 0;
  auto alloc = [&](size_t bytes) -> char* {
    char* p = wsb + off;
    off += (bytes + 255) & ~(size_t)255;
    return p;
  };
  float* sums   = (float*)alloc((size_t)REPL*51200*4);
  float* cnts   = (float*)alloc((size_t)REPL*400*4);
  float* subj1  = (float*)alloc(51200*4);
  float* Tans   = (float*)alloc(4*G3*4);
  float* Tcae   = (float*)alloc(4*G3*4);
  float* Tlab   = (float*)alloc(2*G3*4);
  float* lacc   = (float*)alloc(2*4);
  float* logits = (float*)alloc((size_t)SB*4);
  bf16*  l1Wb   = (bf16*) alloc((size_t)512*512*2);
  bf16*  l2Wb   = (bf16*) alloc((size_t)512*512*2);
  bf16*  WiB    = (bf16*) alloc((size_t)384*256*2);
  bf16*  q1     = (bf16*) alloc((size_t)NQ*DD*2);
  bf16*  pred   = (bf16*) alloc((size_t)SB*PP*2);                 // 52.4 MB
  // shared region: xp2 fp16 (39.3MB + 2-step pad) then h1 bf16 (52.4MB)
  size_t xp2_bytes = ((size_t)SS+2)*TST*2;
  size_t h1_bytes  = (size_t)SB*PP*2;
  char*  xh     = alloc(xp2_bytes > h1_bytes ? xp2_bytes : h1_bytes);
  _Float16* xp2 = (_Float16*)xh;
  bf16*  h1     = (bf16*)xh;   // aliased: xp2 dead after gru_scan
  float* out    = (float*)d_out;

  hipMemsetAsync(sums, 0, (size_t)REPL*(51200+400)*sizeof(float), stream);
  hipMemsetAsync(lacc, 0, 2*sizeof(float), stream);
  hipMemsetAsync(logits, 0, (size_t)SB*sizeof(float), stream);

  tables_k<<<dim3(3), dim3(128), 0, stream>>>(ans_emb, lab_emb, gru_Wi, Tans, Tcae, Tlab);
  conv_w_k<<<dim3(1024), dim3(256), 0, stream>>>(l1_W, l2_W, gru_Wi, l1Wb, l2Wb, WiB);
  q2s_scatter<<<dim3(NQ/QPB), dim3(128), 0, stream>>>(q_emb, q2s_W, q2s_b, q_map, sums, cnts);
  subjects1_k<<<dim3(NS), dim3(128), 0, stream>>>(s_emb, s2s_W, s2s_b, sums, cnts, subj1);
  questions1_k<<<dim3(NQ/QPB), dim3(128), 0, stream>>>(q_emb, subj1, q_map, q_mask,
                                                       s2q_W, s2q_b, q2q_W, q2q_b, q1);
  assemble_k<<<dim3(SB), dim3(128), 0, stream>>>(q1, subj1, ans_emb, cans, sub_ids, smask, q_ids, pred);
  gemm_xp<<<dim3(400,3), dim3(256), 0, stream>>>(pred, WiB, gru_bi, gru_bh, Tans, Tcae, Tlab,
                                                 tm, vm, lm, ans, cans, labels, xp2);
  gru_scan_mfma<<<dim3(16), dim3(512), 0, stream>>>(xp2, gru_Wh, gru_bh, pred);
  gemm_l1<<<dim3(400,4), dim3(256), 0, stream>>>(pred, l1Wb, l1_b, h1);
  gemm_l2_logits<<<dim3(400,4), dim3(256), 0, stream>>>(h1, l2Wb, l2_b, pred, out_W, logits);
  loss_probs_k<<<dim3(SB/256), dim3(256), 0, stream>>>(logits, labels, tm, vm, lm, out_b, out, lacc);
  finalize_k<<<dim3(1), dim3(1), 0, stream>>>(lacc, out);
}

// Round 9
// 922.809 us; speedup vs baseline: 1.1160x; 1.0118x over previous
//
#include <hip/hip_runtime.h>
#include <hip/hip_bf16.h>
#include <math.h>

#define NQ 30000
#define NS 400
#define DD 128
#define HH 128
#define SS 200
#define BB 256
#define MSq 4
#define MBs 4
#define PP 512
#define SB (SS*BB)      // 51200
#define G3 384          // 3*H
#define QPB 16
#define REPL 8          // q2s atomic replicas
#define GBLK 32         // GRU blocks (8 batch each)
#define TST3 (GBLK*3*1024)  // xp3 halfs per timestep

typedef __hip_bfloat16 bf16;
typedef __attribute__((ext_vector_type(8))) short bf16x8;
typedef __attribute__((ext_vector_type(4))) float f32x4;
typedef __attribute__((ext_vector_type(4))) _Float16 f16x4;

__device__ __forceinline__ float sigf(float x){ return 1.0f/(1.0f+expf(-x)); }
__device__ __forceinline__ float sigf2(float x){ return 1.0f/(1.0f+__expf(-x)); }
__device__ __forceinline__ float tanhf2(float x){ return 1.0f - 2.0f/(__expf(2.0f*x)+1.0f); }
__device__ __forceinline__ float bfu2f(unsigned short u){
  unsigned int x = ((unsigned int)u)<<16;
  return __uint_as_float(x);
}

// ---------------- tables ----------------
__global__ __launch_bounds__(128) void tables_k(const float* __restrict__ ans_emb,
        const float* __restrict__ label_emb, const float* __restrict__ Wi,
        float* __restrict__ Tans, float* __restrict__ Tcae, float* __restrict__ Tlab){
  int j = blockIdx.x*128 + threadIdx.x;
  if (j >= G3) return;
  const float* wr = Wi + (size_t)j*640;
  for (int a=0;a<4;a++){
    float acc=0.f;
    for (int k=0;k<DD;k++) acc += ans_emb[a*DD+k]*wr[k];
    Tans[a*G3+j]=acc;
  }
  for (int a=0;a<4;a++){
    float acc=0.f;
    for (int k=0;k<DD;k++) acc += ans_emb[a*DD+k]*wr[128+k];
    Tcae[a*G3+j]=acc;
  }
  for (int l=0;l<2;l++){
    float acc=0.f;
    for (int k=0;k<DD;k++) acc += label_emb[l*DD+k]*wr[256+k];
    Tlab[l*G3+j]=acc;
  }
}

// ---------------- weight convert ----------------
__global__ __launch_bounds__(256) void conv_w_k(const float* __restrict__ l1W,
        const float* __restrict__ l2W, const float* __restrict__ Wi,
        bf16* __restrict__ l1Wb, bf16* __restrict__ l2Wb, bf16* __restrict__ WiB){
  int i = blockIdx.x*256 + threadIdx.x;
  if (i < 512*512){
    l1Wb[i] = __float2bfloat16(l1W[i]);
    l2Wb[i] = __float2bfloat16(l2W[i]);
  }
  if (i < 384*256){
    int j = i >> 8, k = i & 255;
    WiB[i] = __float2bfloat16(Wi[j*640 + 384 + k]);
  }
}

// ---------------- q2s projection + scatter (replicated atomics) ----------------
__global__ __launch_bounds__(128) void q2s_scatter(const float* __restrict__ q_emb,
        const float* __restrict__ W, const float* __restrict__ bias,
        const int* __restrict__ q_map, float* __restrict__ sums, float* __restrict__ cnts){
  __shared__ float qe[QPB][DD];
  int q0 = blockIdx.x*QPB;
  int tid = threadIdx.x;
  float* S = sums + (size_t)(blockIdx.x & (REPL-1))*51200;
  float* C = cnts + (size_t)(blockIdx.x & (REPL-1))*400;
  for (int r=0;r<QPB;r++) qe[r][tid] = q_emb[(size_t)(q0+r)*DD + tid];
  __syncthreads();
  float acc[QPB];
  #pragma unroll
  for (int r=0;r<QPB;r++) acc[r] = bias[tid];
  const float4* wr = (const float4*)(W + (size_t)tid*DD);
  #pragma unroll 4
  for (int k4=0;k4<DD/4;k4++){
    float4 w = wr[k4];
    #pragma unroll
    for (int r=0;r<QPB;r++){
      acc[r] += w.x*qe[r][k4*4] + w.y*qe[r][k4*4+1] + w.z*qe[r][k4*4+2] + w.w*qe[r][k4*4+3];
    }
  }
  for (int r=0;r<QPB;r++){
    int q = q0+r;
    #pragma unroll
    for (int m=0;m<MSq;m++){
      int s = q_map[q*MSq+m];
      atomicAdd(&S[(size_t)s*DD + tid], acc[r]);
      if (tid==0) atomicAdd(&C[s], 1.0f);
    }
  }
}

// ---------------- subjects_1 ----------------
__global__ __launch_bounds__(128) void subjects1_k(const float* __restrict__ s_emb,
        const float* __restrict__ W, const float* __restrict__ bias,
        const float* __restrict__ sums, const float* __restrict__ cnts,
        float* __restrict__ out){
  __shared__ float se[DD];
  int s = blockIdx.x; int tid = threadIdx.x;
  se[tid] = s_emb[(size_t)s*DD+tid];
  __syncthreads();
  float acc = bias[tid];
  const float4* wr = (const float4*)(W + (size_t)tid*DD);
  for (int k4=0;k4<DD/4;k4++){
    float4 w = wr[k4];
    acc += w.x*se[k4*4] + w.y*se[k4*4+1] + w.z*se[k4*4+2] + w.w*se[k4*4+3];
  }
  float c = 0.f, sm = 0.f;
  #pragma unroll
  for (int r=0;r<REPL;r++){
    c  += cnts[r*400 + s];
    sm += sums[(size_t)r*51200 + (size_t)s*DD + tid];
  }
  float v = 0.f;
  if (c > 0.f) v = tanhf(sm/fmaxf(c,1.f) + acc);
  out[(size_t)s*DD+tid] = v;
}

// ---------------- questions_1 (bf16 out) ----------------
__global__ __launch_bounds__(128) void questions1_k(const float* __restrict__ q_emb,
        const float* __restrict__ subj1, const int* __restrict__ q_map,
        const float* __restrict__ q_mask,
        const float* __restrict__ s2qW, const float* __restrict__ s2qb,
        const float* __restrict__ q2qW, const float* __restrict__ q2qb,
        bf16* __restrict__ q1out){
  __shared__ float qe[QPB][DD];
  __shared__ float nq[QPB][DD];
  int q0 = blockIdx.x*QPB; int tid = threadIdx.x;
  for (int r=0;r<QPB;r++){
    int q = q0+r;
    qe[r][tid] = q_emb[(size_t)q*DD+tid];
    float sum=0.f, wsum=0.f;
    #pragma unroll
    for (int m=0;m<MSq;m++){
      float w = q_mask[q*MSq+m];
      sum += subj1[(size_t)q_map[q*MSq+m]*DD + tid]*w;
      wsum += w;
    }
    nq[r][tid] = sum / wsum;
  }
  __syncthreads();
  float acc[QPB];
  #pragma unroll
  for (int r=0;r<QPB;r++) acc[r] = s2qb[tid]+q2qb[tid];
  const float4* w1 = (const float4*)(s2qW + (size_t)tid*DD);
  const float4* w2 = (const float4*)(q2qW + (size_t)tid*DD);
  #pragma unroll 2
  for (int k4=0;k4<DD/4;k4++){
    float4 a = w1[k4]; float4 b = w2[k4];
    #pragma unroll
    for (int r=0;r<QPB;r++){
      acc[r] += a.x*nq[r][k4*4] + a.y*nq[r][k4*4+1] + a.z*nq[r][k4*4+2] + a.w*nq[r][k4*4+3]
              + b.x*qe[r][k4*4] + b.y*qe[r][k4*4+1] + b.z*qe[r][k4*4+2] + b.w*qe[r][k4*4+3];
    }
  }
  for (int r=0;r<QPB;r++) q1out[(size_t)(q0+r)*DD+tid] = __float2bfloat16(tanhf(acc[r]));
}

// ---------------- assemble pred_input cols 0:256 and 384:512 (bf16) ----------------
__global__ __launch_bounds__(128) void assemble_k(const bf16* __restrict__ q1,
        const float* __restrict__ subj1, const float* __restrict__ ans_emb,
        const int* __restrict__ cans, const int* __restrict__ sub_ids,
        const float* __restrict__ sub_mask, const int* __restrict__ q_ids,
        bf16* __restrict__ pred){
  int i = blockIdx.x; int d = threadIdx.x;
  size_t base = (size_t)i*PP;
  pred[base + d] = q1[(size_t)q_ids[i]*DD + d];
  float s = 0.f;
  #pragma unroll
  for (int m=0;m<MBs;m++)
    s += subj1[(size_t)sub_ids[i*MBs+m]*DD+d]*sub_mask[i*MBs+m];
  pred[base+128+d] = __float2bfloat16(s);
  pred[base+384+d] = __float2bfloat16(ans_emb[(size_t)cans[i]*DD + d]);
}

// ---------------- xp3 (fp16, GRU-block-transposed) = pred[:,0:256]@WiB.T + tables + bi (+bh r,z) ----
// layout: xp3[((t*GBLK + b>>3)*3 + g)*1024 + d*8 + (b&7)]
// n-loop inside the block: A panel (pred cols 0:256) HBM-fetched once, L2 re-read.
__global__ __launch_bounds__(256) void gemm_xp(const bf16* __restrict__ pred,
        const bf16* __restrict__ WiB, const float* __restrict__ bi,
        const float* __restrict__ bh,
        const float* __restrict__ Tans, const float* __restrict__ Tcae,
        const float* __restrict__ Tlab,
        const float* __restrict__ tm, const float* __restrict__ vm,
        const float* __restrict__ lm,
        const int* __restrict__ ans, const int* __restrict__ cans,
        const float* __restrict__ labels, _Float16* __restrict__ xp3){
  int lane = threadIdx.x & 63; int wid = threadIdx.x >> 6;
  int wy = wid >> 1, wx = wid & 1;
  int mbase = blockIdx.x*128 + wy*64;
  int lr = lane & 15, kg = (lane >> 4) * 8;
  for (int ny=0; ny<3; ny++){
    int nbase = ny*128 + wx*64;
    f32x4 acc[4][4];
    #pragma unroll
    for (int i=0;i<4;i++)
      #pragma unroll
      for (int j=0;j<4;j++) acc[i][j] = (f32x4){0.f,0.f,0.f,0.f};
    for (int k=0; k<256; k+=32){
      bf16x8 af[4], bfr[4];
      #pragma unroll
      for (int mi=0;mi<4;mi++)
        af[mi] = *(const bf16x8*)(pred + (size_t)(mbase+mi*16+lr)*PP + k + kg);
      #pragma unroll
      for (int ni=0;ni<4;ni++)
        bfr[ni] = *(const bf16x8*)(WiB + (size_t)(nbase+ni*16+lr)*256 + k + kg);
      #pragma unroll
      for (int mi=0;mi<4;mi++)
        #pragma unroll
        for (int ni=0;ni<4;ni++)
          acc[mi][ni] = __builtin_amdgcn_mfma_f32_16x16x32_bf16(af[mi], bfr[ni], acc[mi][ni], 0, 0, 0);
    }
    #pragma unroll
    for (int mi=0;mi<4;mi++){
      #pragma unroll
      for (int r=0;r<4;r++){
        int row = mbase + mi*16 + (lane>>4)*4 + r;
        int t = row >> 8, b = row & 255;
        size_t base = (((size_t)t*GBLK + (b>>3))*3)*1024 + (b&7);
        float mk = tm[row]*vm[row]*lm[row];
        int a = ans[row], ca = cans[row], lb = (int)labels[row];
        #pragma unroll
        for (int ni=0;ni<4;ni++){
          int c = nbase + ni*16 + lr;
          int g = c >> 7, dd = c & 127;
          float v = acc[mi][ni][r] + bi[c]
              + mk*Tans[a*G3+c] + Tcae[ca*G3+c] + mk*Tlab[lb*G3+c];
          if (g < 2) v += bh[c];          // fold r,z hidden bias (n bias stays in GRU)
          xp3[base + (size_t)(g*1024 + dd*8)] = (_Float16)v;
        }
      }
    }
  }
}

// ---------------- fused l1+l2+logits: 64-row tile, h1 in swizzled LDS ----------------
// 800 blocks x 512 thr (8 waves). wave wx covers n-quarter wx*64; one n pass.
// phase1: h1 = relu(pred@l1W+b) -> LDS (XOR swizzle byte^((row&7)<<4));
//         wave0 also accumulates residual pred. outW into logits.
// phase2: h2 = relu(h1_lds@l2W+b); logits += h2.outW.
__global__ __launch_bounds__(512, 1) void gemm_l1l2(const bf16* __restrict__ pred,
        const bf16* __restrict__ W1, const float* __restrict__ b1,
        const bf16* __restrict__ W2, const float* __restrict__ b2,
        const float* __restrict__ outW, float* __restrict__ logits){
  __shared__ __align__(16) char hl[64*1024];   // 64 rows x 512 bf16 cols
  const int lane = threadIdx.x & 63;
  const int wx = threadIdx.x >> 6;        // 0..7 n-quarter
  const int nbase = wx*64;
  const int mbase = blockIdx.x*64;
  const int lr = lane & 15, lg = lane >> 4, kg = lg*8;

  // ---- phase 1 ----
  {
    f32x4 acc[4][4];
    #pragma unroll
    for (int i=0;i<4;i++)
      #pragma unroll
      for (int j=0;j<4;j++) acc[i][j] = (f32x4){0.f,0.f,0.f,0.f};
    float pres[4] = {0.f,0.f,0.f,0.f};
    for (int k=0; k<512; k+=32){
      bf16x8 af[4], bfr[4];
      #pragma unroll
      for (int mi=0;mi<4;mi++)
        af[mi] = *(const bf16x8*)(pred + (size_t)(mbase+mi*16+lr)*PP + k + kg);
      #pragma unroll
      for (int ni=0;ni<4;ni++)
        bfr[ni] = *(const bf16x8*)(W1 + (size_t)(nbase+ni*16+lr)*PP + k + kg);
      #pragma unroll
      for (int mi=0;mi<4;mi++)
        #pragma unroll
        for (int ni=0;ni<4;ni++)
          acc[mi][ni] = __builtin_amdgcn_mfma_f32_16x16x32_bf16(af[mi], bfr[ni], acc[mi][ni], 0, 0, 0);
      if (wx == 0){   // residual pred.outW (each (row,col) exactly once across lanes)
        float4 o0 = *(const float4*)(outW + k + kg);
        float4 o1 = *(const float4*)(outW + k + kg + 4);
        #pragma unroll
        for (int mi=0;mi<4;mi++){
          const unsigned short* au = (const unsigned short*)&af[mi];
          pres[mi] += bfu2f(au[0])*o0.x + bfu2f(au[1])*o0.y + bfu2f(au[2])*o0.z + bfu2f(au[3])*o0.w
                    + bfu2f(au[4])*o1.x + bfu2f(au[5])*o1.y + bfu2f(au[6])*o1.z + bfu2f(au[7])*o1.w;
        }
      }
    }
    // epilogue: relu + bias -> swizzled LDS
    #pragma unroll
    for (int mi=0;mi<4;mi++){
      #pragma unroll
      for (int ni=0;ni<4;ni++){
        int c = nbase + ni*16 + lr;
        float bia = b1[c];
        #pragma unroll
        for (int r=0;r<4;r++){
          int rw = mi*16 + lg*4 + r;
          int addr = (rw*1024 + c*2) ^ ((rw&7)<<4);
          *(bf16*)(hl + addr) = __float2bfloat16(fmaxf(acc[mi][ni][r] + bia, 0.f));
        }
      }
    }
    if (wx == 0){
      #pragma unroll
      for (int mi=0;mi<4;mi++){
        float v = pres[mi];
        v += __shfl_xor(v, 16);
        v += __shfl_xor(v, 32);
        if (lg == 0) atomicAdd(&logits[mbase + mi*16 + lr], v);
      }
    }
  }
  __syncthreads();
  // ---- phase 2 ----
  {
    f32x4 acc[4][4];
    #pragma unroll
    for (int i=0;i<4;i++)
      #pragma unroll
      for (int j=0;j<4;j++) acc[i][j] = (f32x4){0.f,0.f,0.f,0.f};
    for (int k=0; k<512; k+=32){
      bf16x8 af[4], bfr[4];
      #pragma unroll
      for (int mi=0;mi<4;mi++){
        int rw = mi*16 + lr;
        int addr = (rw*1024 + (k+kg)*2) ^ ((rw&7)<<4);
        af[mi] = *(const bf16x8*)(hl + addr);
      }
      #pragma unroll
      for (int ni=0;ni<4;ni++)
        bfr[ni] = *(const bf16x8*)(W2 + (size_t)(nbase+ni*16+lr)*PP + k + kg);
      #pragma unroll
      for (int mi=0;mi<4;mi++)
        #pragma unroll
        for (int ni=0;ni<4;ni++)
          acc[mi][ni] = __builtin_amdgcn_mfma_f32_16x16x32_bf16(af[mi], bfr[ni], acc[mi][ni], 0, 0, 0);
    }
    #pragma unroll
    for (int mi=0;mi<4;mi++){
      #pragma unroll
      for (int r=0;r<4;r++){
        int row = mbase + mi*16 + lg*4 + r;
        float p = 0.f;
        #pragma unroll
        for (int ni=0;ni<4;ni++){
          int c = nbase + ni*16 + lr;
          p += fmaxf(acc[mi][ni][r] + b2[c], 0.f) * outW[c];
        }
        p += __shfl_xor(p,1);
        p += __shfl_xor(p,2);
        p += __shfl_xor(p,4);
        p += __shfl_xor(p,8);
        if (lr == 0) atomicAdd(&logits[row], p);
      }
    }
  }
}

// ================= MFMA GRU scan: 32 blocks x 8 batch, 8-deep prefetch =================
__global__ __launch_bounds__(512, 1) void gru_scan_mfma(const _Float16* __restrict__ xp3,
        const float* __restrict__ Wh, const float* __restrict__ bh,
        bf16* __restrict__ pred){
  __shared__ __align__(16) char hbf[8192];   // 2 x bf16 h[16 rows][128 d]; rows 8-15 stay 0
  const int tid  = threadIdx.x;
  const int lane = tid & 63;
  const int w    = tid >> 6;
  const int lr   = lane & 15;
  const int lg   = lane >> 4;       // 0..3
  const int d    = w*16 + lr;
  const int bg0  = blockIdx.x * 8;

  // ---- Wh fragments (bf16, permanent) ----
  union U8 { bf16x8 v; unsigned short s[8]; };
  bf16x8 wf0[4], wf1[4], wf2[4];
  #pragma unroll
  for (int kk=0; kk<4; kk++){
    #pragma unroll
    for (int g=0; g<3; g++){
      const float* src = Wh + (size_t)(g*HH + d)*HH + kk*32 + lg*8;
      U8 u;
      #pragma unroll
      for (int j=0;j<8;j++){
        bf16 bv = __float2bfloat16(src[j]);
        u.s[j] = reinterpret_cast<unsigned short&>(bv);
      }
      if (g==0) wf0[kk]=u.v; else if (g==1) wf1[kk]=u.v; else wf2[kk]=u.v;
    }
  }
  const float bh2 = bh[2*HH+d];

  int rdaddr[4];
  #pragma unroll
  for (int kk=0;kk<4;kk++) rdaddr[kk] = lr*256 + ((kk*64 + lg*16) ^ ((lr&7)<<4));
  int wraddr[4];
  #pragma unroll
  for (int q=0;q<4;q++){
    int B_ = lg*4 + q;        // valid only lg<2 (batch 0..7)
    wraddr[q] = B_*256 + ((2*d) ^ ((B_&7)<<4));
  }
  // pred flush: threads 0..127 cover 8 rows x 128 d
  const int fB = tid >> 4, fblk = tid & 15;
  const int faddr = fB*256 + ((fblk*16) ^ ((fB&7)<<4));
  bf16* fptr = pred + ((size_t)bg0 + fB)*PP + 256 + fblk*8;
  const size_t PSTRIDE = (size_t)BB*PP;

  float h0=0.f, h1v=0.f, h2v=0.f, h3v=0.f;
  ((unsigned long long*)hbf)[tid]       = 0ULL;
  ((unsigned long long*)hbf)[tid + 512] = 0ULL;

  // x base: lanes lg>=2 mirror lg&1 (same cache lines, values unused)
  const char* xb = (const char*)(xp3 + (size_t)blockIdx.x*3*1024 + d*8 + (lg&1)*4);

#define GSET(s) \
  f16x4 x##s##r = *(const f16x4*)(xb + (size_t)(s)*TST3*2); \
  f16x4 x##s##z = *(const f16x4*)(xb + (size_t)(s)*TST3*2 + 2048); \
  f16x4 x##s##n = *(const f16x4*)(xb + (size_t)(s)*TST3*2 + 4096);
  GSET(0) GSET(1) GSET(2) GSET(3) GSET(4) GSET(5) GSET(6) GSET(7)
#undef GSET

  __syncthreads();

#define GATEQ(Q, CR, CZ, CN, HV) { \
    float r  = sigf2((float)(CR) + ac0[Q]); \
    float zg = sigf2((float)(CZ) + ac1[Q]); \
    float n  = tanhf2((float)(CN) + r*(ac2[Q] + bh2)); \
    HV = (1.f - zg)*n + zg*HV; }

#define GSTEP(s, RO_, WO_) { \
    f32x4 ac0 = (f32x4){0.f,0.f,0.f,0.f}, ac1 = ac0, ac2 = ac0; \
    _Pragma("unroll") for (int kk=0; kk<4; kk++){ \
      bf16x8 a = *(const bf16x8*)(hbf + (RO_) + rdaddr[kk]); \
      ac0 = __builtin_amdgcn_mfma_f32_16x16x32_bf16(a, wf0[kk], ac0, 0,0,0); \
      ac1 = __builtin_amdgcn_mfma_f32_16x16x32_bf16(a, wf1[kk], ac1, 0,0,0); \
      ac2 = __builtin_amdgcn_mfma_f32_16x16x32_bf16(a, wf2[kk], ac2, 0,0,0); \
    } \
    if (tid < 128){  /* flush forward_ht = h(t), coalesced */ \
      int4 hv = *(const int4*)(hbf + (RO_) + faddr); \
      *(int4*)fptr = hv; \
    } \
    fptr += PSTRIDE; \
    GATEQ(0, x##s##r.x, x##s##z.x, x##s##n.x, h0) \
    GATEQ(1, x##s##r.y, x##s##z.y, x##s##n.y, h1v) \
    GATEQ(2, x##s##r.z, x##s##z.z, x##s##n.z, h2v) \
    GATEQ(3, x##s##r.w, x##s##z.w, x##s##n.w, h3v) \
    if (lg < 2){ \
      *(bf16*)(hbf + (WO_) + wraddr[0]) = __float2bfloat16(h0); \
      *(bf16*)(hbf + (WO_) + wraddr[1]) = __float2bfloat16(h1v); \
      *(bf16*)(hbf + (WO_) + wraddr[2]) = __float2bfloat16(h2v); \
      *(bf16*)(hbf + (WO_) + wraddr[3]) = __float2bfloat16(h3v); \
    } \
    x##s##r = *(const f16x4*)(xb + (size_t)((s)+8)*TST3*2); \
    x##s##z = *(const f16x4*)(xb + (size_t)((s)+8)*TST3*2 + 2048); \
    x##s##n = *(const f16x4*)(xb + (size_t)((s)+8)*TST3*2 + 4096); \
    asm volatile("s_waitcnt lgkmcnt(0)" ::: "memory"); \
    __builtin_amdgcn_s_barrier(); \
    __builtin_amdgcn_sched_barrier(0); \
  }

  for (int it=0; it<SS/8; ++it){
    GSTEP(0, 0,    4096)
    GSTEP(1, 4096, 0)
    GSTEP(2, 0,    4096)
    GSTEP(3, 4096, 0)
    GSTEP(4, 0,    4096)
    GSTEP(5, 4096, 0)
    GSTEP(6, 0,    4096)
    GSTEP(7, 4096, 0)
    xb += (size_t)8*TST3*2;
  }
#undef GSTEP
#undef GATEQ
}

// ---------------- loss + probs ----------------
__global__ __launch_bounds__(256) void loss_probs_k(const float* __restrict__ logits,
        const float* __restrict__ labels, const float* __restrict__ tm,
        const float* __restrict__ vm, const float* __restrict__ lm,
        const float* __restrict__ out_b, float* __restrict__ out,
        float* __restrict__ lacc){
  int i = blockIdx.x*256 + threadIdx.x;
  float x = logits[i] + out_b[0];
  float lb = labels[i];
  float mk = tm[i]*vm[i]*lm[i];
  float sp = fmaxf(x,0.f) + log1pf(expf(-fabsf(x)));
  float pe = (sp - x*lb)*mk;
  out[1+i] = sigf(x);
  float v0 = pe, v1 = mk;
  for (int o=32;o>0;o>>=1){ v0 += __shfl_down(v0,o); v1 += __shfl_down(v1,o); }
  if ((threadIdx.x & 63)==0){ atomicAdd(&lacc[0], v0); atomicAdd(&lacc[1], v1); }
}

__global__ void finalize_k(const float* __restrict__ lacc, float* __restrict__ out){
  out[0] = lacc[0]/lacc[1];
}

// ---------------- launch ----------------
extern "C" void kernel_launch(void* const* d_in, const int* in_sizes, int n_in,
                              void* d_out, int out_size, void* d_ws, size_t ws_size,
                              hipStream_t stream) {
  const float* q_emb   = (const float*)d_in[0];
  const float* s_emb   = (const float*)d_in[1];
  const float* ans_emb = (const float*)d_in[2];
  const float* lab_emb = (const float*)d_in[3];
  const float* gru_Wi  = (const float*)d_in[4];
  const float* gru_Wh  = (const float*)d_in[5];
  const float* gru_bi  = (const float*)d_in[6];
  const float* gru_bh  = (const float*)d_in[7];
  const float* s2s_W   = (const float*)d_in[8];
  const float* s2s_b   = (const float*)d_in[9];
  const float* s2q_W   = (const float*)d_in[10];
  const float* s2q_b   = (const float*)d_in[11];
  const float* q2q_W   = (const float*)d_in[12];
  const float* q2q_b   = (const float*)d_in[13];
  const float* q2s_W   = (const float*)d_in[14];
  const float* q2s_b   = (const float*)d_in[15];
  const float* l1_W    = (const float*)d_in[16];
  const float* l1_b    = (const float*)d_in[17];
  const float* l2_W    = (const float*)d_in[18];
  const float* l2_b    = (const float*)d_in[19];
  const float* out_W   = (const float*)d_in[20];
  const float* out_b   = (const float*)d_in[21];
  const float* tm      = (const float*)d_in[22];
  const float* vm      = (const float*)d_in[23];
  const float* lm      = (const float*)d_in[24];
  const float* smask   = (const float*)d_in[25];
  const float* q_mask  = (const float*)d_in[26];
  const float* labels  = (const float*)d_in[27];
  const int*   ans     = (const int*)d_in[28];
  const int*   cans    = (const int*)d_in[29];
  const int*   sub_ids = (const int*)d_in[30];
  const int*   q_ids   = (const int*)d_in[31];
  const int*   q_map   = (const int*)d_in[32];

  // ---- workspace layout ----
  char* wsb = (char*)d_ws;
  size_t off = 0;
  auto alloc = [&](size_t bytes) -> char* {
    char* p = wsb + off;
    off += (bytes + 255) & ~(size_t)255;
    return p;
  };
  float* sums   = (float*)alloc((size_t)REPL*51200*4);
  float* cnts   = (float*)alloc((size_t)REPL*400*4);
  float* subj1  = (float*)alloc(51200*4);
  float* Tans   = (float*)alloc(4*G3*4);
  float* Tcae   = (float*)alloc(4*G3*4);
  float* Tlab   = (float*)alloc(2*G3*4);
  float* lacc   = (float*)alloc(2*4);
  float* logits = (float*)alloc((size_t)SB*4);
  bf16*  l1Wb   = (bf16*) alloc((size_t)512*512*2);
  bf16*  l2Wb   = (bf16*) alloc((size_t)512*512*2);
  bf16*  WiB    = (bf16*) alloc((size_t)384*256*2);
  bf16*  q1     = (bf16*) alloc((size_t)NQ*DD*2);
  bf16*  pred   = (bf16*) alloc((size_t)SB*PP*2);               // 52.4 MB
  _Float16* xp3 = (_Float16*)alloc(((size_t)SS+8)*TST3*2);      // 40.9 MB (8-step prefetch pad)
  float* out    = (float*)d_out;

  hipMemsetAsync(sums, 0, (size_t)REPL*(51200+400)*sizeof(float), stream);
  hipMemsetAsync(lacc, 0, 2*sizeof(float), stream);
  hipMemsetAsync(logits, 0, (size_t)SB*sizeof(float), stream);

  tables_k<<<dim3(3), dim3(128), 0, stream>>>(ans_emb, lab_emb, gru_Wi, Tans, Tcae, Tlab);
  conv_w_k<<<dim3(1024), dim3(256), 0, stream>>>(l1_W, l2_W, gru_Wi, l1Wb, l2Wb, WiB);
  q2s_scatter<<<dim3(NQ/QPB), dim3(128), 0, stream>>>(q_emb, q2s_W, q2s_b, q_map, sums, cnts);
  subjects1_k<<<dim3(NS), dim3(128), 0, stream>>>(s_emb, s2s_W, s2s_b, sums, cnts, subj1);
  questions1_k<<<dim3(NQ/QPB), dim3(128), 0, stream>>>(q_emb, subj1, q_map, q_mask,
                                                       s2q_W, s2q_b, q2q_W, q2q_b, q1);
  assemble_k<<<dim3(SB), dim3(128), 0, stream>>>(q1, subj1, ans_emb, cans, sub_ids, smask, q_ids, pred);
  gemm_xp<<<dim3(400), dim3(256), 0, stream>>>(pred, WiB, gru_bi, gru_bh, Tans, Tcae, Tlab,
                                               tm, vm, lm, ans, cans, labels, xp3);
  gru_scan_mfma<<<dim3(GBLK), dim3(512), 0, stream>>>(xp3, gru_Wh, gru_bh, pred);
  gemm_l1l2<<<dim3(SB/64), dim3(512), 0, stream>>>(pred, l1Wb, l1_b, l2Wb, l2_b, out_W, logits);
  loss_probs_k<<<dim3(SB/256), dim3(256), 0, stream>>>(logits, labels, tm, vm, lm, out_b, out, lacc);
  finalize_k<<<dim3(1), dim3(1), 0, stream>>>(lacc, out);
}

// Round 11
// 779.768 us; speedup vs baseline: 1.3208x; 1.1834x over previous
//
#include <hip/hip_runtime.h>
#include <hip/hip_bf16.h>
#include <math.h>

#define NQ 30000
#define NS 400
#define DD 128
#define HH 128
#define SS 200
#define BB 256
#define MSq 4
#define MBs 4
#define PP 512
#define SB (SS*BB)      // 51200
#define G3 384          // 3*H
#define QPB 16
#define REPL 64         // q2s atomic replicas
#define GBLK 32         // GRU blocks (8 batch each)
#define TST3 (GBLK*3*1024)  // xp3 halfs per timestep

typedef __hip_bfloat16 bf16;
typedef __attribute__((ext_vector_type(8))) short bf16x8;
typedef __attribute__((ext_vector_type(4))) float f32x4;
typedef __attribute__((ext_vector_type(4))) _Float16 f16x4;

__device__ __forceinline__ float sigf(float x){ return 1.0f/(1.0f+expf(-x)); }
// fast gates: v_exp + v_rcp (no IEEE div sequence)
__device__ __forceinline__ float sigr(float x){
  return __builtin_amdgcn_rcpf(1.0f + __expf(-x));
}
__device__ __forceinline__ float tanhr(float x){
  return 1.0f - 2.0f*__builtin_amdgcn_rcpf(__expf(2.0f*x) + 1.0f);
}
__device__ __forceinline__ float bfu2f(unsigned short u){
  unsigned int x = ((unsigned int)u)<<16;
  return __uint_as_float(x);
}

// ---------------- tables ----------------
__global__ __launch_bounds__(128) void tables_k(const float* __restrict__ ans_emb,
        const float* __restrict__ label_emb, const float* __restrict__ Wi,
        float* __restrict__ Tans, float* __restrict__ Tcae, float* __restrict__ Tlab){
  int j = blockIdx.x*128 + threadIdx.x;
  if (j >= G3) return;
  const float* wr = Wi + (size_t)j*640;
  for (int a=0;a<4;a++){
    float acc=0.f;
    for (int k=0;k<DD;k++) acc += ans_emb[a*DD+k]*wr[k];
    Tans[a*G3+j]=acc;
  }
  for (int a=0;a<4;a++){
    float acc=0.f;
    for (int k=0;k<DD;k++) acc += ans_emb[a*DD+k]*wr[128+k];
    Tcae[a*G3+j]=acc;
  }
  for (int l=0;l<2;l++){
    float acc=0.f;
    for (int k=0;k<DD;k++) acc += label_emb[l*DD+k]*wr[256+k];
    Tlab[l*G3+j]=acc;
  }
}

// ---------------- weight convert ----------------
__global__ __launch_bounds__(256) void conv_w_k(const float* __restrict__ l1W,
        const float* __restrict__ l2W, const float* __restrict__ Wi,
        bf16* __restrict__ l1Wb, bf16* __restrict__ l2Wb, bf16* __restrict__ WiB){
  int i = blockIdx.x*256 + threadIdx.x;
  if (i < 512*512){
    l1Wb[i] = __float2bfloat16(l1W[i]);
    l2Wb[i] = __float2bfloat16(l2W[i]);
  }
  if (i < 384*256){
    int j = i >> 8, k = i & 255;
    WiB[i] = __float2bfloat16(Wi[j*640 + 384 + k]);
  }
}

// ---------------- q2s projection + scatter (64-way replicated atomics) ----------------
__global__ __launch_bounds__(128) void q2s_scatter(const float* __restrict__ q_emb,
        const float* __restrict__ W, const float* __restrict__ bias,
        const int* __restrict__ q_map, float* __restrict__ sums, float* __restrict__ cnts){
  __shared__ float qe[QPB][DD];
  int q0 = blockIdx.x*QPB;
  int tid = threadIdx.x;
  float* S = sums + (size_t)(blockIdx.x & (REPL-1))*51200;
  float* C = cnts + (size_t)(blockIdx.x & (REPL-1))*400;
  for (int r=0;r<QPB;r++) qe[r][tid] = q_emb[(size_t)(q0+r)*DD + tid];
  __syncthreads();
  float acc[QPB];
  #pragma unroll
  for (int r=0;r<QPB;r++) acc[r] = bias[tid];
  const float4* wr = (const float4*)(W + (size_t)tid*DD);
  #pragma unroll 4
  for (int k4=0;k4<DD/4;k4++){
    float4 w = wr[k4];
    #pragma unroll
    for (int r=0;r<QPB;r++){
      acc[r] += w.x*qe[r][k4*4] + w.y*qe[r][k4*4+1] + w.z*qe[r][k4*4+2] + w.w*qe[r][k4*4+3];
    }
  }
  for (int r=0;r<QPB;r++){
    int q = q0+r;
    #pragma unroll
    for (int m=0;m<MSq;m++){
      int s = q_map[q*MSq+m];
      atomicAdd(&S[(size_t)s*DD + tid], acc[r]);
      if (tid==0) atomicAdd(&C[s], 1.0f);
    }
  }
}

// ---------------- subjects_1 (reduces 64 replicas) ----------------
__global__ __launch_bounds__(128) void subjects1_k(const float* __restrict__ s_emb,
        const float* __restrict__ W, const float* __restrict__ bias,
        const float* __restrict__ sums, const float* __restrict__ cnts,
        float* __restrict__ out){
  __shared__ float se[DD];
  int s = blockIdx.x; int tid = threadIdx.x;
  se[tid] = s_emb[(size_t)s*DD+tid];
  __syncthreads();
  float acc = bias[tid];
  const float4* wr = (const float4*)(W + (size_t)tid*DD);
  for (int k4=0;k4<DD/4;k4++){
    float4 w = wr[k4];
    acc += w.x*se[k4*4] + w.y*se[k4*4+1] + w.z*se[k4*4+2] + w.w*se[k4*4+3];
  }
  float c = 0.f, sm = 0.f;
  for (int r=0;r<REPL;r++){
    c  += cnts[r*400 + s];
    sm += sums[(size_t)r*51200 + (size_t)s*DD + tid];
  }
  float v = 0.f;
  if (c > 0.f) v = tanhf(sm/fmaxf(c,1.f) + acc);
  out[(size_t)s*DD+tid] = v;
}

// ---------------- questions_1 (bf16 out) ----------------
__global__ __launch_bounds__(128) void questions1_k(const float* __restrict__ q_emb,
        const float* __restrict__ subj1, const int* __restrict__ q_map,
        const float* __restrict__ q_mask,
        const float* __restrict__ s2qW, const float* __restrict__ s2qb,
        const float* __restrict__ q2qW, const float* __restrict__ q2qb,
        bf16* __restrict__ q1out){
  __shared__ float qe[QPB][DD];
  __shared__ float nq[QPB][DD];
  int q0 = blockIdx.x*QPB; int tid = threadIdx.x;
  for (int r=0;r<QPB;r++){
    int q = q0+r;
    qe[r][tid] = q_emb[(size_t)q*DD+tid];
    float sum=0.f, wsum=0.f;
    #pragma unroll
    for (int m=0;m<MSq;m++){
      float w = q_mask[q*MSq+m];
      sum += subj1[(size_t)q_map[q*MSq+m]*DD + tid]*w;
      wsum += w;
    }
    nq[r][tid] = sum / wsum;
  }
  __syncthreads();
  float acc[QPB];
  #pragma unroll
  for (int r=0;r<QPB;r++) acc[r] = s2qb[tid]+q2qb[tid];
  const float4* w1 = (const float4*)(s2qW + (size_t)tid*DD);
  const float4* w2 = (const float4*)(q2qW + (size_t)tid*DD);
  #pragma unroll 2
  for (int k4=0;k4<DD/4;k4++){
    float4 a = w1[k4]; float4 b = w2[k4];
    #pragma unroll
    for (int r=0;r<QPB;r++){
      acc[r] += a.x*nq[r][k4*4] + a.y*nq[r][k4*4+1] + a.z*nq[r][k4*4+2] + a.w*nq[r][k4*4+3]
              + b.x*qe[r][k4*4] + b.y*qe[r][k4*4+1] + b.z*qe[r][k4*4+2] + b.w*qe[r][k4*4+3];
    }
  }
  for (int r=0;r<QPB;r++) q1out[(size_t)(q0+r)*DD+tid] = __float2bfloat16(tanhf(acc[r]));
}

// ---------------- assemble (grid-stride, 1024 blocks) ----------------
__global__ __launch_bounds__(256) void assemble_k(const bf16* __restrict__ q1,
        const float* __restrict__ subj1, const float* __restrict__ ans_emb,
        const int* __restrict__ cans, const int* __restrict__ sub_ids,
        const float* __restrict__ sub_mask, const int* __restrict__ q_ids,
        bf16* __restrict__ pred){
  const int total = SB*DD;
  for (int idx = blockIdx.x*256 + threadIdx.x; idx < total; idx += 1024*256){
    int i = idx >> 7, d = idx & 127;
    size_t base = (size_t)i*PP;
    pred[base + d] = q1[(size_t)q_ids[i]*DD + d];
    float s = 0.f;
    #pragma unroll
    for (int m=0;m<MBs;m++)
      s += subj1[(size_t)sub_ids[i*MBs+m]*DD+d]*sub_mask[i*MBs+m];
    pred[base+128+d] = __float2bfloat16(s);
    pred[base+384+d] = __float2bfloat16(ans_emb[(size_t)cans[i]*DD + d]);
  }
}

// ---------------- xp3 (fp16, GRU-block-transposed): grid (400,3) ----------------
// layout: xp3[((t*GBLK + b>>3)*3 + g)*1024 + d*8 + (b&7)]
__global__ __launch_bounds__(256) void gemm_xp(const bf16* __restrict__ pred,
        const bf16* __restrict__ WiB, const float* __restrict__ bi,
        const float* __restrict__ bh,
        const float* __restrict__ Tans, const float* __restrict__ Tcae,
        const float* __restrict__ Tlab,
        const float* __restrict__ tm, const float* __restrict__ vm,
        const float* __restrict__ lm,
        const int* __restrict__ ans, const int* __restrict__ cans,
        const float* __restrict__ labels, _Float16* __restrict__ xp3){
  int lane = threadIdx.x & 63; int wid = threadIdx.x >> 6;
  int wy = wid >> 1, wx = wid & 1;
  int mbase = blockIdx.x*128 + wy*64;
  int nbase = blockIdx.y*128 + wx*64;
  int lr = lane & 15, kg = (lane >> 4) * 8;
  f32x4 acc[4][4];
  #pragma unroll
  for (int i=0;i<4;i++)
    #pragma unroll
    for (int j=0;j<4;j++) acc[i][j] = (f32x4){0.f,0.f,0.f,0.f};
  for (int k=0; k<256; k+=32){
    bf16x8 af[4], bfr[4];
    #pragma unroll
    for (int mi=0;mi<4;mi++)
      af[mi] = *(const bf16x8*)(pred + (size_t)(mbase+mi*16+lr)*PP + k + kg);
    #pragma unroll
    for (int ni=0;ni<4;ni++)
      bfr[ni] = *(const bf16x8*)(WiB + (size_t)(nbase+ni*16+lr)*256 + k + kg);
    #pragma unroll
    for (int mi=0;mi<4;mi++)
      #pragma unroll
      for (int ni=0;ni<4;ni++)
        acc[mi][ni] = __builtin_amdgcn_mfma_f32_16x16x32_bf16(af[mi], bfr[ni], acc[mi][ni], 0, 0, 0);
  }
  #pragma unroll
  for (int mi=0;mi<4;mi++){
    #pragma unroll
    for (int r=0;r<4;r++){
      int row = mbase + mi*16 + (lane>>4)*4 + r;
      int t = row >> 8, b = row & 255;
      size_t base = (((size_t)t*GBLK + (b>>3))*3)*1024 + (b&7);
      float mk = tm[row]*vm[row]*lm[row];
      int a = ans[row], ca = cans[row], lb = (int)labels[row];
      #pragma unroll
      for (int ni=0;ni<4;ni++){
        int c = nbase + ni*16 + lr;
        int g = c >> 7, dd = c & 127;
        float v = acc[mi][ni][r] + bi[c]
            + mk*Tans[a*G3+c] + Tcae[ca*G3+c] + mk*Tlab[lb*G3+c];
        if (g < 2) v += bh[c];
        xp3[base + (size_t)(g*1024 + dd*8)] = (_Float16)v;
      }
    }
  }
}

// ---------------- fused l1+l2+logits (verified r9) ----------------
__global__ __launch_bounds__(512, 1) void gemm_l1l2(const bf16* __restrict__ pred,
        const bf16* __restrict__ W1, const float* __restrict__ b1,
        const bf16* __restrict__ W2, const float* __restrict__ b2,
        const float* __restrict__ outW, float* __restrict__ logits){
  __shared__ __align__(16) char hl[64*1024];
  const int lane = threadIdx.x & 63;
  const int wx = threadIdx.x >> 6;
  const int nbase = wx*64;
  const int mbase = blockIdx.x*64;
  const int lr = lane & 15, lg = lane >> 4, kg = lg*8;
  {
    f32x4 acc[4][4];
    #pragma unroll
    for (int i=0;i<4;i++)
      #pragma unroll
      for (int j=0;j<4;j++) acc[i][j] = (f32x4){0.f,0.f,0.f,0.f};
    float pres[4] = {0.f,0.f,0.f,0.f};
    for (int k=0; k<512; k+=32){
      bf16x8 af[4], bfr[4];
      #pragma unroll
      for (int mi=0;mi<4;mi++)
        af[mi] = *(const bf16x8*)(pred + (size_t)(mbase+mi*16+lr)*PP + k + kg);
      #pragma unroll
      for (int ni=0;ni<4;ni++)
        bfr[ni] = *(const bf16x8*)(W1 + (size_t)(nbase+ni*16+lr)*PP + k + kg);
      #pragma unroll
      for (int mi=0;mi<4;mi++)
        #pragma unroll
        for (int ni=0;ni<4;ni++)
          acc[mi][ni] = __builtin_amdgcn_mfma_f32_16x16x32_bf16(af[mi], bfr[ni], acc[mi][ni], 0, 0, 0);
      if (wx == 0){
        float4 o0 = *(const float4*)(outW + k + kg);
        float4 o1 = *(const float4*)(outW + k + kg + 4);
        #pragma unroll
        for (int mi=0;mi<4;mi++){
          const unsigned short* au = (const unsigned short*)&af[mi];
          pres[mi] += bfu2f(au[0])*o0.x + bfu2f(au[1])*o0.y + bfu2f(au[2])*o0.z + bfu2f(au[3])*o0.w
                    + bfu2f(au[4])*o1.x + bfu2f(au[5])*o1.y + bfu2f(au[6])*o1.z + bfu2f(au[7])*o1.w;
        }
      }
    }
    #pragma unroll
    for (int mi=0;mi<4;mi++){
      #pragma unroll
      for (int ni=0;ni<4;ni++){
        int c = nbase + ni*16 + lr;
        float bia = b1[c];
        #pragma unroll
        for (int r=0;r<4;r++){
          int rw = mi*16 + lg*4 + r;
          int addr = (rw*1024 + c*2) ^ ((rw&7)<<4);
          *(bf16*)(hl + addr) = __float2bfloat16(fmaxf(acc[mi][ni][r] + bia, 0.f));
        }
      }
    }
    if (wx == 0){
      #pragma unroll
      for (int mi=0;mi<4;mi++){
        float v = pres[mi];
        v += __shfl_xor(v, 16);
        v += __shfl_xor(v, 32);
        if (lg == 0) atomicAdd(&logits[mbase + mi*16 + lr], v);
      }
    }
  }
  __syncthreads();
  {
    f32x4 acc[4][4];
    #pragma unroll
    for (int i=0;i<4;i++)
      #pragma unroll
      for (int j=0;j<4;j++) acc[i][j] = (f32x4){0.f,0.f,0.f,0.f};
    for (int k=0; k<512; k+=32){
      bf16x8 af[4], bfr[4];
      #pragma unroll
      for (int mi=0;mi<4;mi++){
        int rw = mi*16 + lr;
        int addr = (rw*1024 + (k+kg)*2) ^ ((rw&7)<<4);
        af[mi] = *(const bf16x8*)(hl + addr);
      }
      #pragma unroll
      for (int ni=0;ni<4;ni++)
        bfr[ni] = *(const bf16x8*)(W2 + (size_t)(nbase+ni*16+lr)*PP + k + kg);
      #pragma unroll
      for (int mi=0;mi<4;mi++)
        #pragma unroll
        for (int ni=0;ni<4;ni++)
          acc[mi][ni] = __builtin_amdgcn_mfma_f32_16x16x32_bf16(af[mi], bfr[ni], acc[mi][ni], 0, 0, 0);
    }
    #pragma unroll
    for (int mi=0;mi<4;mi++){
      #pragma unroll
      for (int r=0;r<4;r++){
        int row = mbase + mi*16 + lg*4 + r;
        float p = 0.f;
        #pragma unroll
        for (int ni=0;ni<4;ni++){
          int c = nbase + ni*16 + lr;
          p += fmaxf(acc[mi][ni][r] + b2[c], 0.f) * outW[c];
        }
        p += __shfl_xor(p,1);
        p += __shfl_xor(p,2);
        p += __shfl_xor(p,4);
        p += __shfl_xor(p,8);
        if (lr == 0) atomicAdd(&logits[row], p);
      }
    }
  }
}

// ================= MFMA GRU scan: 32 blocks x 8 batch, 2-deep ring, rcp gates =================
__global__ __launch_bounds__(512, 1) void gru_scan_mfma(const _Float16* __restrict__ xp3,
        const float* __restrict__ Wh, const float* __restrict__ bh,
        bf16* __restrict__ pred){
  __shared__ __align__(16) char hbf[8192];
  const int tid  = threadIdx.x;
  const int lane = tid & 63;
  const int w    = tid >> 6;
  const int lr   = lane & 15;
  const int lg   = lane >> 4;
  const int d    = w*16 + lr;
  const int bg0  = blockIdx.x * 8;

  union U8 { bf16x8 v; unsigned short s[8]; };
  bf16x8 wf0[4], wf1[4], wf2[4];
  #pragma unroll
  for (int kk=0; kk<4; kk++){
    #pragma unroll
    for (int g=0; g<3; g++){
      const float* src = Wh + (size_t)(g*HH + d)*HH + kk*32 + lg*8;
      U8 u;
      #pragma unroll
      for (int j=0;j<8;j++){
        bf16 bv = __float2bfloat16(src[j]);
        u.s[j] = reinterpret_cast<unsigned short&>(bv);
      }
      if (g==0) wf0[kk]=u.v; else if (g==1) wf1[kk]=u.v; else wf2[kk]=u.v;
    }
  }
  const float bh2 = bh[2*HH+d];

  int rdaddr[4];
  #pragma unroll
  for (int kk=0;kk<4;kk++) rdaddr[kk] = lr*256 + ((kk*64 + lg*16) ^ ((lr&7)<<4));
  int wraddr[4];
  #pragma unroll
  for (int q=0;q<4;q++){
    int B_ = lg*4 + q;
    wraddr[q] = B_*256 + ((2*d) ^ ((B_&7)<<4));
  }
  const int fB = tid >> 4, fblk = tid & 15;
  const int faddr = fB*256 + ((fblk*16) ^ ((fB&7)<<4));
  bf16* fptr = pred + ((size_t)bg0 + fB)*PP + 256 + fblk*8;
  const size_t PSTRIDE = (size_t)BB*PP;

  float h0=0.f, h1v=0.f, h2v=0.f, h3v=0.f;
  ((unsigned long long*)hbf)[tid]       = 0ULL;
  ((unsigned long long*)hbf)[tid + 512] = 0ULL;

  const char* xb = (const char*)(xp3 + (size_t)blockIdx.x*3*1024 + d*8 + (lg&1)*4);
  f16x4 xrA = *(const f16x4*)(xb);
  f16x4 xzA = *(const f16x4*)(xb + 2048);
  f16x4 xnA = *(const f16x4*)(xb + 4096);
  f16x4 xrB = *(const f16x4*)(xb + (size_t)TST3*2);
  f16x4 xzB = *(const f16x4*)(xb + (size_t)TST3*2 + 2048);
  f16x4 xnB = *(const f16x4*)(xb + (size_t)TST3*2 + 4096);
  const char* xt = xb + 2*(size_t)TST3*2;

  __syncthreads();

#define GATEQ(Q, CR, CZ, CN, HV) { \
    float r  = sigr((float)(CR) + ac0[Q]); \
    float zg = sigr((float)(CZ) + ac1[Q]); \
    float n  = tanhr((float)(CN) + r*(ac2[Q] + bh2)); \
    HV = (1.f - zg)*n + zg*HV; }

#define GSTEP(RO_, WO_, XR, XZ, XN) { \
    f32x4 ac0 = (f32x4){0.f,0.f,0.f,0.f}, ac1 = ac0, ac2 = ac0; \
    _Pragma("unroll") for (int kk=0; kk<4; kk++){ \
      bf16x8 a = *(const bf16x8*)(hbf + (RO_) + rdaddr[kk]); \
      ac0 = __builtin_amdgcn_mfma_f32_16x16x32_bf16(a, wf0[kk], ac0, 0,0,0); \
      ac1 = __builtin_amdgcn_mfma_f32_16x16x32_bf16(a, wf1[kk], ac1, 0,0,0); \
      ac2 = __builtin_amdgcn_mfma_f32_16x16x32_bf16(a, wf2[kk], ac2, 0,0,0); \
    } \
    if (tid < 128){ \
      int4 hv = *(const int4*)(hbf + (RO_) + faddr); \
      *(int4*)fptr = hv; \
    } \
    fptr += PSTRIDE; \
    GATEQ(0, (XR).x, (XZ).x, (XN).x, h0) \
    GATEQ(1, (XR).y, (XZ).y, (XN).y, h1v) \
    GATEQ(2, (XR).z, (XZ).z, (XN).z, h2v) \
    GATEQ(3, (XR).w, (XZ).w, (XN).w, h3v) \
    if (lg < 2){ \
      *(bf16*)(hbf + (WO_) + wraddr[0]) = __float2bfloat16(h0); \
      *(bf16*)(hbf + (WO_) + wraddr[1]) = __float2bfloat16(h1v); \
      *(bf16*)(hbf + (WO_) + wraddr[2]) = __float2bfloat16(h2v); \
      *(bf16*)(hbf + (WO_) + wraddr[3]) = __float2bfloat16(h3v); \
    } \
    XR = *(const f16x4*)(xt); \
    XZ = *(const f16x4*)(xt + 2048); \
    XN = *(const f16x4*)(xt + 4096); \
    xt += (size_t)TST3*2; \
    asm volatile("s_waitcnt lgkmcnt(0)" ::: "memory"); \
    __builtin_amdgcn_s_barrier(); \
    __builtin_amdgcn_sched_barrier(0); \
  }

  for (int t=0; t<SS; t+=2){
    GSTEP(0,    4096, xrA, xzA, xnA)
    GSTEP(4096, 0,    xrB, xzB, xnB)
  }
#undef GSTEP
#undef GATEQ
}

// ---------------- loss + probs ----------------
__global__ __launch_bounds__(256) void loss_probs_k(const float* __restrict__ logits,
        const float* __restrict__ labels, const float* __restrict__ tm,
        const float* __restrict__ vm, const float* __restrict__ lm,
        const float* __restrict__ out_b, float* __restrict__ out,
        float* __restrict__ lacc){
  int i = blockIdx.x*256 + threadIdx.x;
  float x = logits[i] + out_b[0];
  float lb = labels[i];
  float mk = tm[i]*vm[i]*lm[i];
  float sp = fmaxf(x,0.f) + log1pf(expf(-fabsf(x)));
  float pe = (sp - x*lb)*mk;
  out[1+i] = sigf(x);
  float v0 = pe, v1 = mk;
  for (int o=32;o>0;o>>=1){ v0 += __shfl_down(v0,o); v1 += __shfl_down(v1,o); }
  if ((threadIdx.x & 63)==0){ atomicAdd(&lacc[0], v0); atomicAdd(&lacc[1], v1); }
}

__global__ void finalize_k(const float* __restrict__ lacc, float* __restrict__ out){
  out[0] = lacc[0]/lacc[1];
}

// ---------------- launch ----------------
extern "C" void kernel_launch(void* const* d_in, const int* in_sizes, int n_in,
                              void* d_out, int out_size, void* d_ws, size_t ws_size,
                              hipStream_t stream) {
  const float* q_emb   = (const float*)d_in[0];
  const float* s_emb   = (const float*)d_in[1];
  const float* ans_emb = (const float*)d_in[2];
  const float* lab_emb = (const float*)d_in[3];
  const float* gru_Wi  = (const float*)d_in[4];
  const float* gru_Wh  = (const float*)d_in[5];
  const float* gru_bi  = (const float*)d_in[6];
  const float* gru_bh  = (const float*)d_in[7];
  const float* s2s_W   = (const float*)d_in[8];
  const float* s2s_b   = (const float*)d_in[9];
  const float* s2q_W   = (const float*)d_in[10];
  const float* s2q_b   = (const float*)d_in[11];
  const float* q2q_W   = (const float*)d_in[12];
  const float* q2q_b   = (const float*)d_in[13];
  const float* q2s_W   = (const float*)d_in[14];
  const float* q2s_b   = (const float*)d_in[15];
  const float* l1_W    = (const float*)d_in[16];
  const float* l1_b    = (const float*)d_in[17];
  const float* l2_W    = (const float*)d_in[18];
  const float* l2_b    = (const float*)d_in[19];
  const float* out_W   = (const float*)d_in[20];
  const float* out_b   = (const float*)d_in[21];
  const float* tm      = (const float*)d_in[22];
  const float* vm      = (const float*)d_in[23];
  const float* lm      = (const float*)d_in[24];
  const float* smask   = (const float*)d_in[25];
  const float* q_mask  = (const float*)d_in[26];
  const float* labels  = (const float*)d_in[27];
  const int*   ans     = (const int*)d_in[28];
  const int*   cans    = (const int*)d_in[29];
  const int*   sub_ids = (const int*)d_in[30];
  const int*   q_ids   = (const int*)d_in[31];
  const int*   q_map   = (const int*)d_in[32];

  char* wsb = (char*)d_ws;
  size_t off = 0;
  auto alloc = [&](size_t bytes) -> char* {
    char* p = wsb + off;
    off += (bytes + 255) & ~(size_t)255;
    return p;
  };
  float* sums   = (float*)alloc((size_t)REPL*51200*4);   // 13.1 MB
  float* cnts   = (float*)alloc((size_t)REPL*400*4);
  float* subj1  = (float*)alloc(51200*4);
  float* Tans   = (float*)alloc(4*G3*4);
  float* Tcae   = (float*)alloc(4*G3*4);
  float* Tlab   = (float*)alloc(2*G3*4);
  float* lacc   = (float*)alloc(2*4);
  float* logits = (float*)alloc((size_t)SB*4);
  bf16*  l1Wb   = (bf16*) alloc((size_t)512*512*2);
  bf16*  l2Wb   = (bf16*) alloc((size_t)512*512*2);
  bf16*  WiB    = (bf16*) alloc((size_t)384*256*2);
  bf16*  q1     = (bf16*) alloc((size_t)NQ*DD*2);
  bf16*  pred   = (bf16*) alloc((size_t)SB*PP*2);               // 52.4 MB
  _Float16* xp3 = (_Float16*)alloc(((size_t)SS+4)*TST3*2);      // 40 MB
  float* out    = (float*)d_out;

  hipMemsetAsync(sums, 0, (size_t)REPL*(51200+400)*sizeof(float), stream);
  hipMemsetAsync(lacc, 0, 2*sizeof(float), stream);
  hipMemsetAsync(logits, 0, (size_t)SB*sizeof(float), stream);

  tables_k<<<dim3(3), dim3(128), 0, stream>>>(ans_emb, lab_emb, gru_Wi, Tans, Tcae, Tlab);
  conv_w_k<<<dim3(1024), dim3(256), 0, stream>>>(l1_W, l2_W, gru_Wi, l1Wb, l2Wb, WiB);
  q2s_scatter<<<dim3(NQ/QPB), dim3(128), 0, stream>>>(q_emb, q2s_W, q2s_b, q_map, sums, cnts);
  subjects1_k<<<dim3(NS), dim3(128), 0, stream>>>(s_emb, s2s_W, s2s_b, sums, cnts, subj1);
  questions1_k<<<dim3(NQ/QPB), dim3(128), 0, stream>>>(q_emb, subj1, q_map, q_mask,
                                                       s2q_W, s2q_b, q2q_W, q2q_b, q1);
  assemble_k<<<dim3(1024), dim3(256), 0, stream>>>(q1, subj1, ans_emb, cans, sub_ids, smask, q_ids, pred);
  gemm_xp<<<dim3(400,3), dim3(256), 0, stream>>>(pred, WiB, gru_bi, gru_bh, Tans, Tcae, Tlab,
                                                 tm, vm, lm, ans, cans, labels, xp3);
  gru_scan_mfma<<<dim3(GBLK), dim3(512), 0, stream>>>(xp3, gru_Wh, gru_bh, pred);
  gemm_l1l2<<<dim3(SB/64), dim3(512), 0, stream>>>(pred, l1Wb, l1_b, l2Wb, l2_b, out_W, logits);
  loss_probs_k<<<dim3(SB/256), dim3(256), 0, stream>>>(logits, labels, tm, vm, lm, out_b, out, lacc);
  finalize_k<<<dim3(1), dim3(1), 0, stream>>>(lacc, out);
}